// Round 13
// baseline (336.755 us; speedup 1.0000x reference)
//
#include <hip/hip_runtime.h>
#include <math.h>

#define NN 200000
#define EEDGE 500000
#define BB 4096
#define KK 20
#define MM 100000
#define Q3 (3*BB)
#define NBLK ((NN + 255) / 256)
#define S1R 48

typedef _Float16 __attribute__((ext_vector_type(8))) f16x8;
typedef _Float16 __attribute__((ext_vector_type(4))) f16x4;
typedef float __attribute__((ext_vector_type(4))) f32x4;

#define MFMA16(a,b,c) __builtin_amdgcn_mfma_f32_16x16x32_f16(a,b,c,0,0,0)

// cos(a) for |a| up to ~1e7: f64 range-reduction to revolutions + v_cos_f32.
__device__ __forceinline__ float fast_cos(float a) {
    double ad = (double)a * 0.15915494309189535;   // 1/(2*pi)
    double fr = ad - floor(ad);                    // [0,1) revolutions
    return __builtin_amdgcn_cosf((float)fr);       // cos(2*pi*x)
}

// time encoding matching numpy's f32 arg rounding — NO fma contraction.
__device__ __forceinline__ float tenc(float dt, float w, float b) {
    float p = __fmul_rn(dt, w);
    float a = __fadd_rn(p, b);
    return fast_cos(a);
}

__device__ __forceinline__ float fsigm(float x) {
    return __builtin_amdgcn_rcpf(1.f + __expf(-x));
}
__device__ __forceinline__ float ftanh(float x) {
    return 1.f - 2.f * __builtin_amdgcn_rcpf(1.f + __expf(2.f * x));
}

__device__ __forceinline__ f32x4 z4() {
    f32x4 v; v[0] = 0.f; v[1] = 0.f; v[2] = 0.f; v[3] = 0.f; return v;
}

__global__ void k_init(int* lastpos, char* mask) {
    int i = blockIdx.x * 256 + threadIdx.x;
    if (i < NN) { lastpos[i] = -1; mask[i] = 0; }
}

__global__ void k_scatter(const int* __restrict__ msg_src, int* __restrict__ lastpos) {
    int i = blockIdx.x * 256 + threadIdx.x;
    if (i < MM) atomicMax(&lastpos[msg_src[i]], i);
}

// mark nodes whose feat row is actually read (query nodes + all neighbors)
__global__ void k_mark(const int* __restrict__ src_nodes, const int* __restrict__ dst_nodes,
                       const int* __restrict__ neg_nodes, const int* __restrict__ neighbors,
                       char* __restrict__ mask) {
    int i = blockIdx.x * 256 + threadIdx.x;
    if (i < Q3) {
        int node = (i < BB) ? src_nodes[i] : (i < 2 * BB) ? dst_nodes[i - BB] : neg_nodes[i - 2 * BB];
        mask[node] = 1;
    } else {
        int e = i - Q3;
        if (e < Q3 * KK) mask[neighbors[e]] = 1;
    }
}

// ordered (sorted-by-node) compaction: count -> scan -> fill (R9-proven)
__global__ void k_count(const int* __restrict__ lastpos, int* __restrict__ bcnt) {
    int n = blockIdx.x * 256 + threadIdx.x;
    int flag = (n < NN && lastpos[n] >= 0) ? 1 : 0;
    unsigned long long m = __ballot(flag != 0);
    __shared__ int wc[4];
    int wave = threadIdx.x >> 6, lane = threadIdx.x & 63;
    if (lane == 0) wc[wave] = __popcll(m);
    __syncthreads();
    if (threadIdx.x == 0) bcnt[blockIdx.x] = wc[0] + wc[1] + wc[2] + wc[3];
}

__global__ void k_scan(const int* __restrict__ bcnt, int* __restrict__ boff,
                       int* __restrict__ count) {
    __shared__ int s[NBLK];
    int t = threadIdx.x;
    for (int i = t; i < NBLK; i += 256) s[i] = bcnt[i];
    __syncthreads();
    if (t == 0) {
        int acc = 0;
        for (int i = 0; i < NBLK; i++) { int v = s[i]; s[i] = acc; acc += v; }
        *count = acc;
    }
    __syncthreads();
    for (int i = t; i < NBLK; i += 256) boff[i] = s[i];
}

// fill also initializes inv (-1 for non-message nodes)
__global__ void k_fill(const int* __restrict__ lastpos, const int* __restrict__ boff,
                       int* __restrict__ comp, int* __restrict__ inv) {
    int n = blockIdx.x * 256 + threadIdx.x;
    int flag = (n < NN && lastpos[n] >= 0) ? 1 : 0;
    unsigned long long m = __ballot(flag != 0);
    __shared__ int wc[4];
    int wave = threadIdx.x >> 6, lane = threadIdx.x & 63;
    if (lane == 0) wc[wave] = __popcll(m);
    __syncthreads();
    int base = boff[blockIdx.x];
    for (int i = 0; i < wave; i++) base += wc[i];
    int rank = __popcll(m & ((1ull << lane) - 1));
    if (n < NN) {
        int pos = base + rank;
        if (flag) comp[pos] = n;
        inv[n] = flag ? pos : -1;
    }
}

// f32 -> f16 weight conversion into MFMA FRAGMENT ORDER; block 304 = bq2 prep.
// elem offset = matbase + ((cgrp*KS + ks)*64 + lane)*8 + e
__global__ void k_cvtw(const float* __restrict__ W1, const float* __restrict__ W2,
                       const float* __restrict__ Wi, const float* __restrict__ Wh,
                       const float* __restrict__ Wq, const float* __restrict__ Wv,
                       const float* __restrict__ Wo, const float* __restrict__ mW1,
                       const float* __restrict__ mW2, const float* __restrict__ Wk,
                       const float* __restrict__ bq, const float* __restrict__ time_b,
                       _Float16* __restrict__ dst, float* __restrict__ bq2) {
    if (blockIdx.x == 304) {   // bq2[c] = bq[c] + Wq_right[c] . cos(time_b)
        __shared__ float cte[128];
        int t = threadIdx.x;
        if (t < 128) cte[t] = fast_cos(time_b[t]);
        __syncthreads();
        float acc = bq[t];
        #pragma unroll 4
        for (int d = 0; d < 128; d++)
            acc += Wq[(size_t)t * 256 + 128 + d] * cte[d];
        bq2[t] = acc;
        return;
    }
    int f = blockIdx.x * 256 + threadIdx.x;   // fragment id, 77824 total
    if (f >= 77824) return;
    const float* src; int dstoff, K, ldb, lf, tr = -1;
    if      (f < 16384) { src = W1;  dstoff = 0;      K = 512; ldb = 512; lf = f; }
    else if (f < 20480) { src = W2;  dstoff = 131072; K = 256; ldb = 256; lf = f - 16384; }
    else if (f < 26624) { src = Wi;  dstoff = 163840; K = 128; ldb = 128; lf = f - 20480; }
    else if (f < 32768) { src = Wh;  dstoff = 212992; K = 128; ldb = 128; lf = f - 26624; }
    else if (f < 36864) { src = Wq;  dstoff = 262144; K = 128; ldb = 256; lf = f - 32768; } // Wq left half
    else if (f < 43008) { src = Wv;  dstoff = 294912; K = 384; ldb = 384; lf = f - 36864; }
    else if (f < 49152) { src = Wv + 128 * 384; dstoff = 344064; K = 384; ldb = 384; lf = f - 43008; }
    else if (f < 57344) { src = Wo;  dstoff = 393216; K = 256; ldb = 256; lf = f - 49152; }
    else if (f < 63488) { src = mW1; dstoff = 458752; K = 384; ldb = 384; lf = f - 57344; }
    else if (f < 65536) { src = mW2; dstoff = 507904; K = 128; ldb = 128; lf = f - 63488; }
    else if (f < 71680) { src = Wk;  dstoff = 524288; K = 128; ldb = 0; lf = f - 65536; tr = 0; }
    else                { src = Wk;  dstoff = 573440; K = 128; ldb = 0; lf = f - 71680; tr = 1; }
    int KS = K >> 5;
    int cgrp = lf / (KS * 64);
    int rem  = lf - cgrp * (KS * 64);
    int ks = rem >> 6, lane = rem & 63;
    int kg = lane >> 4, arow = lane & 15;
    int col = cgrp * 16 + arow;
    int k0 = ks * 32 + kg * 8;
    f16x8 h;
    if (tr < 0) {
        const float* p = src + (size_t)col * ldb + k0;
        float4 a = *(const float4*)p;
        float4 b = *(const float4*)(p + 4);
        h[0] = (_Float16)a.x; h[1] = (_Float16)a.y; h[2] = (_Float16)a.z; h[3] = (_Float16)a.w;
        h[4] = (_Float16)b.x; h[5] = (_Float16)b.y; h[6] = (_Float16)b.z; h[7] = (_Float16)b.w;
    } else {
        #pragma unroll
        for (int e = 0; e < 8; e++)
            h[e] = (_Float16)Wk[(size_t)(tr * 128 + k0 + e) * 384 + col];
    }
    *(f16x8*)(dst + dstoff + (size_t)lf * 8) = h;
}

// ---------------- Stage 1: 48 rows/block, 512 threads / 8 waves, 3 blocks/CU ----------------
__device__ __forceinline__ int SWA(int r, int byteofs) {
    return r * 1024 + (byteofs ^ ((r & 7) << 4));
}

__device__ __forceinline__ f16x8 ldw4(const _Float16* W, int cg, int ks, int lane) {
    return *(const f16x8*)(W + (((size_t)cg * 4 + ks) * 64 + lane) * 8);
}

__global__ __launch_bounds__(512, 6)
void k_stage1(const int* __restrict__ comp, const int* __restrict__ count,
              const int* __restrict__ lastpos,
              const int* __restrict__ msg_dst, const int* __restrict__ msg_eidx,
              const int* __restrict__ msg_t, const int* __restrict__ last_update,
              const float* __restrict__ memory, const float* __restrict__ edge_feats,
              const float* __restrict__ time_w, const float* __restrict__ time_b,
              const _Float16* __restrict__ W1h, const float* __restrict__ b1,
              const _Float16* __restrict__ W2h, const float* __restrict__ b2,
              const _Float16* __restrict__ Wih, const _Float16* __restrict__ Whh,
              const float* __restrict__ bi, const float* __restrict__ bh,
              _Float16* __restrict__ new_mem)
{
    __shared__ char rawb[S1R * 1024];
    __shared__ int sn[S1R], sd[S1R], se[S1R];
    __shared__ float sdt[S1R];

    int cnt = *count;
    int r0 = blockIdx.x * S1R;
    if (r0 >= cnt) return;
    int tid = threadIdx.x;

    if (tid < S1R) {
        int rr = r0 + tid;
        int j = (rr < cnt) ? rr : r0;
        int n = comp[j];
        int idx = lastpos[n];
        sn[tid] = n;
        sd[tid] = msg_dst[idx];
        se[tid] = msg_eidx[idx];
        sdt[tid] = (float)(msg_t[idx] - last_update[n]);
    }
    __syncthreads();

    for (int gi = tid; gi < S1R * 48; gi += 512) {
        int r = gi / 48, g = gi - r * 48;
        const float* src;
        if (g < 16)      src = memory + (size_t)sn[r] * 128 + g * 8;
        else if (g < 32) src = memory + (size_t)sd[r] * 128 + (g - 16) * 8;
        else             src = edge_feats + (size_t)se[r] * 128 + (g - 32) * 8;
        float4 a = *(const float4*)src;
        float4 b = *(const float4*)(src + 4);
        f16x8 h;
        h[0] = (_Float16)a.x; h[1] = (_Float16)a.y; h[2] = (_Float16)a.z; h[3] = (_Float16)a.w;
        h[4] = (_Float16)b.x; h[5] = (_Float16)b.y; h[6] = (_Float16)b.z; h[7] = (_Float16)b.w;
        *(f16x8*)(rawb + SWA(r, g * 16)) = h;
    }
    for (int gi = tid; gi < S1R * 16; gi += 512) {
        int r = gi >> 4, g = gi & 15;
        int c = g * 8;
        float dt = sdt[r];
        float4 w0 = *(const float4*)(time_w + c);
        float4 w1 = *(const float4*)(time_w + c + 4);
        float4 t0 = *(const float4*)(time_b + c);
        float4 t1 = *(const float4*)(time_b + c + 4);
        f16x8 h;
        h[0] = (_Float16)tenc(dt, w0.x, t0.x); h[1] = (_Float16)tenc(dt, w0.y, t0.y);
        h[2] = (_Float16)tenc(dt, w0.z, t0.z); h[3] = (_Float16)tenc(dt, w0.w, t0.w);
        h[4] = (_Float16)tenc(dt, w1.x, t1.x); h[5] = (_Float16)tenc(dt, w1.y, t1.y);
        h[6] = (_Float16)tenc(dt, w1.z, t1.z); h[7] = (_Float16)tenc(dt, w1.w, t1.w);
        *(f16x8*)(rawb + SWA(r, (48 + g) * 16)) = h;
    }
    __syncthreads();

    int wv = tid >> 6, lane = tid & 63;
    int arow = lane & 15, kg = lane >> 4;

    // GEMM1: h1[48][256], K=512; wave owns 2 col-groups, 3 row-tiles
    f32x4 acc1[2][3];
    #pragma unroll
    for (int c = 0; c < 2; c++)
        #pragma unroll
        for (int rt = 0; rt < 3; rt++) acc1[c][rt] = z4();
    for (int ks = 0; ks < 16; ks++) {
        f16x8 a[3];
        #pragma unroll
        for (int rt = 0; rt < 3; rt++)
            a[rt] = *(const f16x8*)(rawb + SWA(rt * 16 + arow, ks * 64 + kg * 16));
        #pragma unroll
        for (int c = 0; c < 2; c++) {
            f16x8 b = *(const f16x8*)(W1h + (((size_t)(wv * 2 + c) * 16 + ks) * 64 + lane) * 8);
            #pragma unroll
            for (int rt = 0; rt < 3; rt++)
                acc1[c][rt] = MFMA16(a[rt], b, acc1[c][rt]);
        }
    }
    __syncthreads();

    #pragma unroll
    for (int c = 0; c < 2; c++) {
        int col = (wv * 2 + c) * 16 + arow;
        float bb = b1[col];
        #pragma unroll
        for (int rt = 0; rt < 3; rt++)
            #pragma unroll
            for (int rg = 0; rg < 4; rg++) {
                int row = rt * 16 + kg * 4 + rg;
                float v = fmaxf(acc1[c][rt][rg] + bb, 0.f);
                *(_Float16*)(rawb + SWA(row, 384 + col * 2)) = (_Float16)v;
            }
    }
    __syncthreads();

    // GEMM2: msg[48][128], K=256
    f32x4 acc2[3];
    #pragma unroll
    for (int rt = 0; rt < 3; rt++) acc2[rt] = z4();
    for (int ks = 0; ks < 8; ks++) {
        f16x8 b = *(const f16x8*)(W2h + (((size_t)wv * 8 + ks) * 64 + lane) * 8);
        #pragma unroll
        for (int rt = 0; rt < 3; rt++) {
            f16x8 a = *(const f16x8*)(rawb + SWA(rt * 16 + arow, 384 + ks * 64 + kg * 16));
            acc2[rt] = MFMA16(a, b, acc2[rt]);
        }
    }
    __syncthreads();

    {
        int col = wv * 16 + arow;
        float bb = b2[col];
        #pragma unroll
        for (int rt = 0; rt < 3; rt++)
            #pragma unroll
            for (int rg = 0; rg < 4; rg++) {
                int row = rt * 16 + kg * 4 + rg;
                *(_Float16*)(rawb + SWA(row, 384 + col * 2)) =
                    (_Float16)(acc2[rt][rg] + bb);
            }
    }
    __syncthreads();

    // GRU gates, one gate-pass at a time
    f32x4 aR[3], aZ[3], aNi[3], aNh[3];
    #pragma unroll
    for (int rt = 0; rt < 3; rt++) { aR[rt] = z4(); aZ[rt] = z4(); aNi[rt] = z4(); aNh[rt] = z4(); }
    for (int ks = 0; ks < 4; ks++) {
        f16x8 bi_ = ldw4(Wih, wv, ks, lane);
        f16x8 bh_ = ldw4(Whh, wv, ks, lane);
        #pragma unroll
        for (int rt = 0; rt < 3; rt++) {
            f16x8 m = *(const f16x8*)(rawb + SWA(rt * 16 + arow, 384 + ks * 64 + kg * 16));
            f16x8 hh = *(const f16x8*)(rawb + SWA(rt * 16 + arow, ks * 64 + kg * 16));
            aR[rt] = MFMA16(m, bi_, aR[rt]);
            aR[rt] = MFMA16(hh, bh_, aR[rt]);
        }
    }
    for (int ks = 0; ks < 4; ks++) {
        f16x8 bi_ = ldw4(Wih, 8 + wv, ks, lane);
        f16x8 bh_ = ldw4(Whh, 8 + wv, ks, lane);
        #pragma unroll
        for (int rt = 0; rt < 3; rt++) {
            f16x8 m = *(const f16x8*)(rawb + SWA(rt * 16 + arow, 384 + ks * 64 + kg * 16));
            f16x8 hh = *(const f16x8*)(rawb + SWA(rt * 16 + arow, ks * 64 + kg * 16));
            aZ[rt] = MFMA16(m, bi_, aZ[rt]);
            aZ[rt] = MFMA16(hh, bh_, aZ[rt]);
        }
    }
    for (int ks = 0; ks < 4; ks++) {
        f16x8 bi_ = ldw4(Wih, 16 + wv, ks, lane);
        f16x8 bh_ = ldw4(Whh, 16 + wv, ks, lane);
        #pragma unroll
        for (int rt = 0; rt < 3; rt++) {
            f16x8 m = *(const f16x8*)(rawb + SWA(rt * 16 + arow, 384 + ks * 64 + kg * 16));
            f16x8 hh = *(const f16x8*)(rawb + SWA(rt * 16 + arow, ks * 64 + kg * 16));
            aNi[rt] = MFMA16(m, bi_, aNi[rt]);
            aNh[rt] = MFMA16(hh, bh_, aNh[rt]);
        }
    }

    {
        int col = wv * 16 + arow;
        float bir = bi[col],        bhr = bh[col];
        float biz = bi[128 + col],  bhz = bh[128 + col];
        float bin_ = bi[256 + col], bhn_ = bh[256 + col];
        #pragma unroll
        for (int rt = 0; rt < 3; rt++)
            #pragma unroll
            for (int rg = 0; rg < 4; rg++) {
                int row = rt * 16 + kg * 4 + rg;
                int rr = r0 + row;
                if (rr < cnt) {
                    float r_ = fsigm(aR[rt][rg] + bir + bhr);
                    float zg = fsigm(aZ[rt][rg] + biz + bhz);
                    float ng = ftanh(aNi[rt][rg] + bin_ + r_ * (aNh[rt][rg] + bhn_));
                    float om = (float)*(const _Float16*)(rawb + SWA(row, col * 2));
                    new_mem[(size_t)rr * 128 + col] = (_Float16)((1.f - zg) * ng + zg * om);
                }
            }
    }
}

// k_feat: feat[n] = (updated ? new_mem[inv[n]] : memory[n]) + node_feats[n], f16.
// Only for referenced nodes (mask).
__global__ __launch_bounds__(256)
void k_feat(const int* __restrict__ inv, const char* __restrict__ mask,
            const _Float16* __restrict__ new_mem,
            const float* __restrict__ memory, const float* __restrict__ node_feats,
            _Float16* __restrict__ feat)
{
    int idx = blockIdx.x * 256 + threadIdx.x;
    if (idx >= NN * 16) return;
    int n = idx >> 4, g = idx & 15;
    if (!mask[n]) return;
    int c = g * 8;
    int iv = inv[n];
    float4 n0 = *(const float4*)(node_feats + (size_t)n * 128 + c);
    float4 n1 = *(const float4*)(node_feats + (size_t)n * 128 + c + 4);
    f16x8 o;
    if (iv >= 0) {
        f16x8 mv = *(const f16x8*)(new_mem + (size_t)iv * 128 + c);
        o[0] = (_Float16)((float)mv[0] + n0.x); o[1] = (_Float16)((float)mv[1] + n0.y);
        o[2] = (_Float16)((float)mv[2] + n0.z); o[3] = (_Float16)((float)mv[3] + n0.w);
        o[4] = (_Float16)((float)mv[4] + n1.x); o[5] = (_Float16)((float)mv[5] + n1.y);
        o[6] = (_Float16)((float)mv[6] + n1.z); o[7] = (_Float16)((float)mv[7] + n1.w);
    } else {
        float4 m0 = *(const float4*)(memory + (size_t)n * 128 + c);
        float4 m1 = *(const float4*)(memory + (size_t)n * 128 + c + 4);
        o[0] = (_Float16)(m0.x + n0.x); o[1] = (_Float16)(m0.y + n0.y);
        o[2] = (_Float16)(m0.z + n0.z); o[3] = (_Float16)(m0.w + n0.w);
        o[4] = (_Float16)(m1.x + n1.x); o[5] = (_Float16)(m1.y + n1.y);
        o[6] = (_Float16)(m1.z + n1.z); o[7] = (_Float16)(m1.w + n1.w);
    }
    *(f16x8*)(feat + (size_t)n * 128 + c) = o;
}

// ---------------- Stage 2 (R12-exact) ----------------
__global__ __launch_bounds__(512, 2)
void k2b(const int* __restrict__ src_nodes, const int* __restrict__ dst_nodes,
         const int* __restrict__ neg_nodes, const _Float16* __restrict__ feat,
         const _Float16* __restrict__ WqLh, const float* __restrict__ bq2,
         const _Float16* __restrict__ Wkth,
         _Float16* __restrict__ sfeat, _Float16* __restrict__ qk_ws)
{
    __shared__ char lds[24 * 1024];    // [0,8K): sfeat tile; [8K,24K): q tile
    __shared__ int snode[32];
    int tid = threadIdx.x;
    int r0 = blockIdx.x * 32;

    if (tid < 32) {
        int q = r0 + tid;
        snode[tid] = (q < BB) ? src_nodes[q] : (q < 2 * BB) ? dst_nodes[q - BB] : neg_nodes[q - 2 * BB];
    }
    __syncthreads();

    {
        int r = tid >> 4, g = tid & 15;
        f16x8 v = *(const f16x8*)(feat + (size_t)snode[r] * 128 + g * 8);
        *(f16x8*)(&lds[r * 256 + ((g * 16) ^ ((r & 7) << 4))]) = v;
        *(f16x8*)(sfeat + (size_t)(r0 + r) * 128 + g * 8) = v;
    }
    __syncthreads();

    int wv = tid >> 6, lane = tid & 63;
    int arow = lane & 15, kg = lane >> 4;

    f32x4 acc[2][2];
    #pragma unroll
    for (int c = 0; c < 2; c++) { acc[c][0] = z4(); acc[c][1] = z4(); }
    for (int ks = 0; ks < 4; ks++) {
        f16x8 a0 = *(const f16x8*)(&lds[arow * 256 + ((ks * 64 + kg * 16) ^ ((arow & 7) << 4))]);
        f16x8 a1 = *(const f16x8*)(&lds[(16 + arow) * 256 + ((ks * 64 + kg * 16) ^ ((arow & 7) << 4))]);
        #pragma unroll
        for (int c = 0; c < 2; c++) {
            f16x8 b = *(const f16x8*)(WqLh + (((size_t)(wv * 2 + c) * 4 + ks) * 64 + lane) * 8);
            acc[c][0] = MFMA16(a0, b, acc[c][0]);
            acc[c][1] = MFMA16(a1, b, acc[c][1]);
        }
    }
    #pragma unroll
    for (int c = 0; c < 2; c++) {
        int col = (wv * 2 + c) * 16 + arow;
        float bb = bq2[col];
        #pragma unroll
        for (int rt = 0; rt < 2; rt++)
            #pragma unroll
            for (int rg = 0; rg < 4; rg++) {
                int row = rt * 16 + kg * 4 + rg;
                *(_Float16*)(&lds[8192 + row * 512 + ((col * 2) ^ ((row & 7) << 4))]) =
                    (_Float16)(acc[c][rt][rg] + bb);
            }
    }
    __syncthreads();

    int h = wv >> 2;
    f32x4 acc2[6][2];
    #pragma unroll
    for (int c = 0; c < 6; c++) { acc2[c][0] = z4(); acc2[c][1] = z4(); }
    for (int ks = 0; ks < 4; ks++) {
        f16x8 a0 = *(const f16x8*)(&lds[8192 + arow * 512 +
                    ((h * 256 + ks * 64 + kg * 16) ^ ((arow & 7) << 4))]);
        f16x8 a1 = *(const f16x8*)(&lds[8192 + (16 + arow) * 512 +
                    ((h * 256 + ks * 64 + kg * 16) ^ ((arow & 7) << 4))]);
        #pragma unroll
        for (int c = 0; c < 6; c++) {
            int cgh = (wv & 3) * 6 + c;
            f16x8 b = *(const f16x8*)(Wkth + (size_t)h * 49152 +
                       (((size_t)cgh * 4 + ks) * 64 + lane) * 8);
            acc2[c][0] = MFMA16(a0, b, acc2[c][0]);
            acc2[c][1] = MFMA16(a1, b, acc2[c][1]);
        }
    }
    #pragma unroll
    for (int c = 0; c < 6; c++) {
        int cgh = (wv & 3) * 6 + c;
        int col = h * 384 + cgh * 16 + arow;
        #pragma unroll
        for (int rt = 0; rt < 2; rt++)
            #pragma unroll
            for (int rg = 0; rg < 4; rg++) {
                int row = rt * 16 + kg * 4 + rg;
                qk_ws[(size_t)(r0 + row) * 768 + col] = (_Float16)acc2[c][rt][rg];
            }
    }
}

// generic 32-row-tile MFMA GEMM, fragment-ordered B (used for Wv fold only).
template<int KD, int NFRAG, bool RELU>
__global__ __launch_bounds__(256, 4)
void k_gemm(const _Float16* __restrict__ A, int lda, int a_ys,
            const _Float16* __restrict__ B, int b_ys,
            const float* __restrict__ bias, int bias_ys,
            _Float16* __restrict__ C, int ldc, int c_ys,
            float* __restrict__ C32,
            const int* __restrict__ rowmask)
{
    constexpr int ROWB = KD * 2;
    __shared__ char As[32 * ROWB];
    int tid = threadIdx.x;
    int r0 = blockIdx.x * 32;
    int aoff = blockIdx.y * a_ys;
    const _Float16* Bp = B + (size_t)blockIdx.y * b_ys;
    int coff = blockIdx.y * c_ys;

    #pragma unroll
    for (int t = 0; t < (32 * KD / 8) / 256; t++) {
        int gi = tid + t * 256;
        int r = gi / (KD / 8), g = gi % (KD / 8);
        f16x8 v = *(const f16x8*)(A + (size_t)(r0 + r) * lda + aoff + g * 8);
        *(f16x8*)(&As[r * ROWB + ((g * 16) ^ ((r & 7) << 4))]) = v;
    }
    __syncthreads();

    int wv = tid >> 6, lane = tid & 63;
    int arow = lane & 15, kg = lane >> 4;
    f32x4 acc[NFRAG][2];
    #pragma unroll
    for (int c = 0; c < NFRAG; c++) { acc[c][0] = z4(); acc[c][1] = z4(); }

    #pragma unroll
    for (int ks = 0; ks < KD / 32; ks++) {
        f16x8 a0 = *(const f16x8*)(&As[arow * ROWB + ((ks * 64 + kg * 16) ^ ((arow & 7) << 4))]);
        f16x8 a1 = *(const f16x8*)(&As[(16 + arow) * ROWB + ((ks * 64 + kg * 16) ^ ((arow & 7) << 4))]);
        #pragma unroll
        for (int c = 0; c < NFRAG; c++) {
            f16x8 b = *(const f16x8*)(Bp +
                (((size_t)(wv * NFRAG + c) * (KD / 32) + ks) * 64 + lane) * 8);
            acc[c][0] = MFMA16(a0, b, acc[c][0]);
            acc[c][1] = MFMA16(a1, b, acc[c][1]);
        }
    }

    #pragma unroll
    for (int c = 0; c < NFRAG; c++) {
        int cg = (wv * NFRAG + c) * 16 + arow;
        float bb = bias ? bias[blockIdx.y * bias_ys + cg] : 0.f;
        #pragma unroll
        for (int rt = 0; rt < 2; rt++)
            #pragma unroll
            for (int rg = 0; rg < 4; rg++) {
                int grow = r0 + rt * 16 + kg * 4 + rg;
                float v = acc[c][rt][rg] + bb;
                if (RELU) v = fmaxf(v, 0.f);
                if (rowmask && rowmask[grow]) v = 0.f;
                if (C)   C[(size_t)grow * ldc + coff + cg] = (_Float16)v;
                if (C32) C32[(size_t)grow * ldc + coff + cg] = v;
            }
    }
}

// k2d: attention core (R12-exact).
__global__ __launch_bounds__(256)
void k2d(const int* __restrict__ neighbors, const int* __restrict__ nb_eidx,
         const int* __restrict__ nb_et, const int* __restrict__ edge_times,
         const _Float16* __restrict__ feat,
         const float* __restrict__ edge_feats, const float* __restrict__ time_w,
         const float* __restrict__ time_b,
         _Float16* __restrict__ qk_wsum, int* __restrict__ allm)
{
    int tid = threadIdx.x;
    int qi = blockIdx.x * 4 + (tid >> 6);
    int lane = tid & 63;
    int h = lane >> 5, l32 = lane & 31;
    int c0 = l32 * 4;

    float4 tw = *(const float4*)(time_w + c0);
    float4 tb = *(const float4*)(time_b + c0);

    const _Float16* qkp = qk_wsum + (size_t)qi * 768 + h * 384;
    f16x4 t0 = *(const f16x4*)(qkp + c0);
    f16x4 t1 = *(const f16x4*)(qkp + 128 + c0);
    f16x4 t2 = *(const f16x4*)(qkp + 256 + c0);
    float qk0[4], qk1[4], qk2[4];
    #pragma unroll
    for (int t = 0; t < 4; t++) { qk0[t] = (float)t0[t]; qk1[t] = (float)t1[t]; qk2[t] = (float)t2[t]; }

    float ts = (float)edge_times[qi & (BB - 1)];
    float m_run = -3.0e38f, l_run = 0.f;
    float w0[4] = {0,0,0,0}, w1[4] = {0,0,0,0}, w2[4] = {0,0,0,0};
    int anyv = 0;
    const float inv_sqrt = 0.08838834764831845f;

    int base = qi * KK;
    int nb_c = neighbors[base];
    int ei_c = nb_eidx[base];
    int et_c = nb_et[base];
    f16x4 fv;
    float4 ef;
    {
        fv = *(const f16x4*)(feat + (size_t)nb_c * 128 + c0);
        ef = *(const float4*)(edge_feats + (size_t)ei_c * 128 + c0);
    }

    for (int j = 0; j < KK; j++) {
        int nb_n = 0, ei_n = 0, et_n = 0;
        f16x4 fv_n = {0,0,0,0};
        float4 ef_n = {0,0,0,0};
        if (j + 1 < KK) {
            nb_n = neighbors[base + j + 1];
            ei_n = nb_eidx[base + j + 1];
            et_n = nb_et[base + j + 1];
            fv_n = *(const f16x4*)(feat + (size_t)nb_n * 128 + c0);
            ef_n = *(const float4*)(edge_feats + (size_t)ei_n * 128 + c0);
        }

        float dtf = ts - (float)et_c;
        anyv |= (nb_c != 0);
        float k0[4] = { (float)fv[0], (float)fv[1], (float)fv[2], (float)fv[3] };
        float k1[4] = { tenc(dtf, tw.x, tb.x), tenc(dtf, tw.y, tb.y),
                        tenc(dtf, tw.z, tb.z), tenc(dtf, tw.w, tb.w) };
        float k2[4] = { ef.x, ef.y, ef.z, ef.w };

        float sp = 0.f;
        #pragma unroll
        for (int t = 0; t < 4; t++)
            sp += qk0[t] * k0[t] + qk1[t] * k1[t] + qk2[t] * k2[t];
        sp += __shfl_xor(sp, 1, 32);
        sp += __shfl_xor(sp, 2, 32);
        sp += __shfl_xor(sp, 4, 32);
        sp += __shfl_xor(sp, 8, 32);
        sp += __shfl_xor(sp, 16, 32);

        float s = sp * inv_sqrt;
        if (nb_c == 0) s = -1e9f;
        float m_new = fmaxf(m_run, s);
        float sc = __expf(m_run - m_new);
        float p = __expf(s - m_new);
        l_run = l_run * sc + p;
        #pragma unroll
        for (int t = 0; t < 4; t++) {
            w0[t] = w0[t] * sc + p * k0[t];
            w1[t] = w1[t] * sc + p * k1[t];
            w2[t] = w2[t] * sc + p * k2[t];
        }
        m_run = m_new;

        nb_c = nb_n; ei_c = ei_n; et_c = et_n;
        fv = fv_n; ef = ef_n;
    }

    float linv = __builtin_amdgcn_rcpf(l_run);
    _Float16* wp = qk_wsum + (size_t)qi * 768 + h * 384;
    f16x4 o0, o1, o2;
    #pragma unroll
    for (int t = 0; t < 4; t++) {
        o0[t] = (_Float16)(w0[t] * linv);
        o1[t] = (_Float16)(w1[t] * linv);
        o2[t] = (_Float16)(w2[t] * linv);
    }
    *(f16x4*)(wp + c0) = o0;
    *(f16x4*)(wp + 128 + c0) = o1;
    *(f16x4*)(wp + 256 + c0) = o2;
    if (lane == 0) allm[qi] = anyv ? 0 : 1;
}

// k2t2: fused tail (R12-exact, staging fixed at 4 iters).
__global__ __launch_bounds__(256, 2)
void k2t2(const _Float16* __restrict__ ctx, const _Float16* __restrict__ sfeat,
          const _Float16* __restrict__ Woh, const float* __restrict__ bo,
          const _Float16* __restrict__ mW1h, const float* __restrict__ mb1,
          const _Float16* __restrict__ mW2h, const float* __restrict__ mb2,
          const int* __restrict__ allm, float* __restrict__ out)
{
    __shared__ char lds[48 * 1024];
    int tid = threadIdx.x;
    int r0 = blockIdx.x * 32;

    #pragma unroll
    for (int t = 0; t < 4; t++) {
        int gi = tid + t * 256;
        int r = gi >> 5, g = gi & 31;
        f16x8 v = *(const f16x8*)(ctx + (size_t)(r0 + r) * 256 + g * 8);
        *(f16x8*)(&lds[r * 512 + ((g * 16) ^ ((r & 7) << 4))]) = v;
    }
    __syncthreads();

    int wv = tid >> 6, lane = tid & 63;
    int arow = lane & 15, kg = lane >> 4;

    f32x4 acc[4][2];
    #pragma unroll
    for (int c = 0; c < 4; c++) { acc[c][0] = z4(); acc[c][1] = z4(); }
    for (int ks = 0; ks < 8; ks++) {
        f16x8 a0 = *(const f16x8*)(&lds[arow * 512 + ((ks * 64 + kg * 16) ^ ((arow & 7) << 4))]);
        f16x8 a1 = *(const f16x8*)(&lds[(16 + arow) * 512 + ((ks * 64 + kg * 16) ^ ((arow & 7) << 4))]);
        #pragma unroll
        for (int c = 0; c < 4; c++) {
            f16x8 b = *(const f16x8*)(Woh + (((size_t)(wv * 4 + c) * 8 + ks) * 64 + lane) * 8);
            acc[c][0] = MFMA16(a0, b, acc[c][0]);
            acc[c][1] = MFMA16(a1, b, acc[c][1]);
        }
    }
    #pragma unroll
    for (int c = 0; c < 4; c++) {
        int col = (wv * 4 + c) * 16 + arow;
        float bb = bo[col];
        #pragma unroll
        for (int rt = 0; rt < 2; rt++)
            #pragma unroll
            for (int rg = 0; rg < 4; rg++) {
                int row = rt * 16 + kg * 4 + rg;
                float v = allm[r0 + row] ? 0.f : (acc[c][rt][rg] + bb);
                *(_Float16*)(&lds[16384 + row * 768 + ((col * 2) ^ ((row & 7) << 4))]) = (_Float16)v;
            }
    }
    #pragma unroll
    for (int t = 0; t < 2; t++) {
        int gi = tid + t * 256;
        int r = gi >> 4, g = gi & 15;
        f16x8 v = *(const f16x8*)(sfeat + (size_t)(r0 + r) * 128 + g * 8);
        *(f16x8*)(&lds[16384 + r * 768 + ((512 + g * 16) ^ ((r & 7) << 4))]) = v;
    }
    __syncthreads();

    f32x4 acc2[2][2];
    #pragma unroll
    for (int c = 0; c < 2; c++) { acc2[c][0] = z4(); acc2[c][1] = z4(); }
    for (int ks = 0; ks < 12; ks++) {
        f16x8 a0 = *(const f16x8*)(&lds[16384 + arow * 768 + ((ks * 64 + kg * 16) ^ ((arow & 7) << 4))]);
        f16x8 a1 = *(const f16x8*)(&lds[16384 + (16 + arow) * 768 + ((ks * 64 + kg * 16) ^ ((arow & 7) << 4))]);
        #pragma unroll
        for (int c = 0; c < 2; c++) {
            f16x8 b = *(const f16x8*)(mW1h + (((size_t)(wv * 2 + c) * 12 + ks) * 64 + lane) * 8);
            acc2[c][0] = MFMA16(a0, b, acc2[c][0]);
            acc2[c][1] = MFMA16(a1, b, acc2[c][1]);
        }
    }
    #pragma unroll
    for (int c = 0; c < 2; c++) {
        int col = (wv * 2 + c) * 16 + arow;
        float bb = mb1[col];
        #pragma unroll
        for (int rt = 0; rt < 2; rt++)
            #pragma unroll
            for (int rg = 0; rg < 4; rg++) {
                int row = rt * 16 + kg * 4 + rg;
                float v = fmaxf(acc2[c][rt][rg] + bb, 0.f);
                *(_Float16*)(&lds[40960 + row * 256 + ((col * 2) ^ ((row & 7) << 4))]) = (_Float16)v;
            }
    }
    __syncthreads();

    f32x4 acc3[2][2];
    #pragma unroll
    for (int c = 0; c < 2; c++) { acc3[c][0] = z4(); acc3[c][1] = z4(); }
    for (int ks = 0; ks < 4; ks++) {
        f16x8 a0 = *(const f16x8*)(&lds[40960 + arow * 256 + ((ks * 64 + kg * 16) ^ ((arow & 7) << 4))]);
        f16x8 a1 = *(const f16x8*)(&lds[40960 + (16 + arow) * 256 + ((ks * 64 + kg * 16) ^ ((arow & 7) << 4))]);
        #pragma unroll
        for (int c = 0; c < 2; c++) {
            f16x8 b = *(const f16x8*)(mW2h + (((size_t)(wv * 2 + c) * 4 + ks) * 64 + lane) * 8);
            acc3[c][0] = MFMA16(a0, b, acc3[c][0]);
            acc3[c][1] = MFMA16(a1, b, acc3[c][1]);
        }
    }
    #pragma unroll
    for (int c = 0; c < 2; c++) {
        int col = (wv * 2 + c) * 16 + arow;
        float bb = mb2[col];
        #pragma unroll
        for (int rt = 0; rt < 2; rt++)
            #pragma unroll
            for (int rg = 0; rg < 4; rg++) {
                int row = rt * 16 + kg * 4 + rg;
                out[(size_t)(r0 + row) * 128 + col] = acc3[c][rt][rg] + bb;
            }
    }
}

extern "C" void kernel_launch(void* const* d_in, const int* in_sizes, int n_in,
                              void* d_out, int out_size, void* d_ws, size_t ws_size,
                              hipStream_t stream) {
    (void)in_sizes; (void)n_in; (void)out_size; (void)ws_size;
    const int* src_nodes  = (const int*)d_in[0];
    const int* dst_nodes  = (const int*)d_in[1];
    const int* neg_nodes  = (const int*)d_in[2];
    const int* edge_times = (const int*)d_in[3];
    const int* neighbors  = (const int*)d_in[4];
    const int* nb_eidx    = (const int*)d_in[5];
    const int* nb_et      = (const int*)d_in[6];
    const int* msg_src    = (const int*)d_in[7];
    const int* msg_dst    = (const int*)d_in[8];
    const int* msg_eidx   = (const int*)d_in[9];
    const int* msg_t      = (const int*)d_in[10];
    const int* last_update= (const int*)d_in[11];
    const float* node_feats = (const float*)d_in[12];
    const float* edge_feats = (const float*)d_in[13];
    const float* memory     = (const float*)d_in[14];
    const float* time_w = (const float*)d_in[15];
    const float* time_b = (const float*)d_in[16];
    const float* W1 = (const float*)d_in[17];
    const float* b1 = (const float*)d_in[18];
    const float* W2 = (const float*)d_in[19];
    const float* b2 = (const float*)d_in[20];
    const float* gWi = (const float*)d_in[21];
    const float* gWh = (const float*)d_in[22];
    const float* gbi = (const float*)d_in[23];
    const float* gbh = (const float*)d_in[24];
    const float* Wq = (const float*)d_in[25];
    const float* bq = (const float*)d_in[26];
    const float* Wk = (const float*)d_in[27];
    const float* bk = (const float*)d_in[28];
    const float* Wv = (const float*)d_in[29];
    const float* bv = (const float*)d_in[30];
    const float* Wo = (const float*)d_in[31];
    const float* bo = (const float*)d_in[32];
    const float* mW1 = (const float*)d_in[33];
    const float* mb1 = (const float*)d_in[34];
    const float* mW2 = (const float*)d_in[35];
    const float* mb2 = (const float*)d_in[36];
    float* out = (float*)d_out;
    (void)bk;

    char* w = (char*)d_ws;
    int* lastpos = (int*)w;
    int* inv  = lastpos + NN;
    int* comp = inv + NN;
    int* count = comp + NN;
    int* bcnt = count + 1;
    int* boff = bcnt + NBLK;
    char* mask = (char*)(boff + NBLK);                // NN bytes
    size_t off = ((size_t)(3 * NN + 1 + 2 * NBLK) * 4 + NN + 255) & ~(size_t)255;
    _Float16* new_mem = (_Float16*)(w + off);         // MM*128 f16
    size_t foff = off + (size_t)MM * 128 * 2;
    _Float16* feat = (_Float16*)(w + foff);           // NN*128 f16
    size_t woff = foff + (size_t)NN * 128 * 2;

    _Float16* Hpool = (_Float16*)(w + woff);          // 622592 f16, fragment order
    _Float16* W1h  = Hpool;
    _Float16* W2h  = Hpool + 131072;
    _Float16* Wih  = Hpool + 163840;
    _Float16* Whh  = Hpool + 212992;
    _Float16* WqLh = Hpool + 262144;
    _Float16* Wvh  = Hpool + 294912;
    _Float16* Woh  = Hpool + 393216;
    _Float16* mW1h = Hpool + 458752;
    _Float16* mW2h = Hpool + 507904;
    _Float16* Wkth = Hpool + 524288;
    float* bq2 = (float*)(Hpool + 622592);            // 256 f32
    size_t boff2 = woff + (size_t)622592 * 2 + 1024;

    _Float16* ctx   = (_Float16*)(w + boff2);         // Q3*256
    _Float16* qk_ws = ctx + (size_t)Q3 * 256;         // Q3*768
    _Float16* sfeat = qk_ws + (size_t)Q3 * 768;       // Q3*128
    int* allm       = (int*)(sfeat + (size_t)Q3 * 128);

    k_init<<<dim3(NBLK), dim3(256), 0, stream>>>(lastpos, mask);
    k_scatter<<<dim3((MM + 255) / 256), dim3(256), 0, stream>>>(msg_src, lastpos);
    k_mark<<<dim3((Q3 + Q3 * KK + 255) / 256), dim3(256), 0, stream>>>(
        src_nodes, dst_nodes, neg_nodes, neighbors, mask);
    k_count<<<dim3(NBLK), dim3(256), 0, stream>>>(lastpos, bcnt);
    k_scan<<<dim3(1), dim3(256), 0, stream>>>(bcnt, boff, count);
    k_fill<<<dim3(NBLK), dim3(256), 0, stream>>>(lastpos, boff, comp, inv);
    k_cvtw<<<dim3(305), dim3(256), 0, stream>>>(
        W1, W2, gWi, gWh, Wq, Wv, Wo, mW1, mW2, Wk, bq, time_b, Hpool, bq2);
    k_stage1<<<dim3((MM + S1R - 1) / S1R), dim3(512), 0, stream>>>(
        comp, count, lastpos, msg_dst, msg_eidx, msg_t, last_update,
        memory, edge_feats, time_w, time_b,
        W1h, b1, W2h, b2, Wih, Whh, gbi, gbh, new_mem);
    k_feat<<<dim3(NN * 16 / 256), dim3(256), 0, stream>>>(
        inv, mask, new_mem, memory, node_feats, feat);

    k2b<<<dim3(Q3 / 32), dim3(512), 0, stream>>>(
        src_nodes, dst_nodes, neg_nodes, feat, WqLh, bq2, Wkth, sfeat, qk_ws);
    k2d<<<dim3(Q3 / 4), dim3(256), 0, stream>>>(
        neighbors, nb_eidx, nb_et, edge_times, feat,
        edge_feats, time_w, time_b, qk_ws, allm);
    k_gemm<384, 2, false><<<dim3(Q3 / 32, 2), dim3(256), 0, stream>>>(
        qk_ws, 768, 384, Wvh, 49152, bv, 128, ctx, 256, 128, nullptr, nullptr);
    k2t2<<<dim3(Q3 / 32), dim3(256), 0, stream>>>(
        ctx, sfeat, Woh, bo, mW1h, mb1, mW2h, mb2, allm, out);
}

// Round 14
// 281.675 us; speedup vs baseline: 1.1955x; 1.1955x over previous
//
#include <hip/hip_runtime.h>
#include <math.h>

#define NN 200000
#define EEDGE 500000
#define BB 4096
#define KK 20
#define MM 100000
#define Q3 (3*BB)
#define NBLK ((NN + 255) / 256)

typedef _Float16 __attribute__((ext_vector_type(8))) f16x8;
typedef _Float16 __attribute__((ext_vector_type(4))) f16x4;
typedef float __attribute__((ext_vector_type(4))) f32x4;

#define MFMA16(a,b,c) __builtin_amdgcn_mfma_f32_16x16x32_f16(a,b,c,0,0,0)

// cos(a) for |a| up to ~1e7: f64 range-reduction to revolutions + v_cos_f32.
__device__ __forceinline__ float fast_cos(float a) {
    double ad = (double)a * 0.15915494309189535;   // 1/(2*pi)
    double fr = ad - floor(ad);                    // [0,1) revolutions
    return __builtin_amdgcn_cosf((float)fr);       // cos(2*pi*x)
}

// time encoding matching numpy's f32 arg rounding — NO fma contraction.
__device__ __forceinline__ float tenc(float dt, float w, float b) {
    float p = __fmul_rn(dt, w);
    float a = __fadd_rn(p, b);
    return fast_cos(a);
}

__device__ __forceinline__ float fsigm(float x) {
    return __builtin_amdgcn_rcpf(1.f + __expf(-x));
}
__device__ __forceinline__ float ftanh(float x) {
    return 1.f - 2.f * __builtin_amdgcn_rcpf(1.f + __expf(2.f * x));
}

__device__ __forceinline__ f32x4 z4() {
    f32x4 v; v[0] = 0.f; v[1] = 0.f; v[2] = 0.f; v[3] = 0.f; return v;
}

__global__ void k_init(int* lastpos, char* mask) {
    int i = blockIdx.x * 256 + threadIdx.x;
    if (i < NN) { lastpos[i] = -1; mask[i] = 0; }
}

__global__ void k_scatter(const int* __restrict__ msg_src, int* __restrict__ lastpos) {
    int i = blockIdx.x * 256 + threadIdx.x;
    if (i < MM) atomicMax(&lastpos[msg_src[i]], i);
}

// mark nodes whose feat row is actually read (query nodes + all neighbors)
__global__ void k_mark(const int* __restrict__ src_nodes, const int* __restrict__ dst_nodes,
                       const int* __restrict__ neg_nodes, const int* __restrict__ neighbors,
                       char* __restrict__ mask) {
    int i = blockIdx.x * 256 + threadIdx.x;
    if (i < Q3) {
        int node = (i < BB) ? src_nodes[i] : (i < 2 * BB) ? dst_nodes[i - BB] : neg_nodes[i - 2 * BB];
        mask[node] = 1;
    } else {
        int e = i - Q3;
        if (e < Q3 * KK) mask[neighbors[e]] = 1;
    }
}

// ordered (sorted-by-node) compaction: count -> scan -> fill (R9-proven)
__global__ void k_count(const int* __restrict__ lastpos, int* __restrict__ bcnt) {
    int n = blockIdx.x * 256 + threadIdx.x;
    int flag = (n < NN && lastpos[n] >= 0) ? 1 : 0;
    unsigned long long m = __ballot(flag != 0);
    __shared__ int wc[4];
    int wave = threadIdx.x >> 6, lane = threadIdx.x & 63;
    if (lane == 0) wc[wave] = __popcll(m);
    __syncthreads();
    if (threadIdx.x == 0) bcnt[blockIdx.x] = wc[0] + wc[1] + wc[2] + wc[3];
}

__global__ void k_scan(const int* __restrict__ bcnt, int* __restrict__ boff,
                       int* __restrict__ count) {
    __shared__ int s[NBLK];
    int t = threadIdx.x;
    for (int i = t; i < NBLK; i += 256) s[i] = bcnt[i];
    __syncthreads();
    if (t == 0) {
        int acc = 0;
        for (int i = 0; i < NBLK; i++) { int v = s[i]; s[i] = acc; acc += v; }
        *count = acc;
    }
    __syncthreads();
    for (int i = t; i < NBLK; i += 256) boff[i] = s[i];
}

// fill also initializes inv (-1 for non-message nodes)
__global__ void k_fill(const int* __restrict__ lastpos, const int* __restrict__ boff,
                       int* __restrict__ comp, int* __restrict__ inv) {
    int n = blockIdx.x * 256 + threadIdx.x;
    int flag = (n < NN && lastpos[n] >= 0) ? 1 : 0;
    unsigned long long m = __ballot(flag != 0);
    __shared__ int wc[4];
    int wave = threadIdx.x >> 6, lane = threadIdx.x & 63;
    if (lane == 0) wc[wave] = __popcll(m);
    __syncthreads();
    int base = boff[blockIdx.x];
    for (int i = 0; i < wave; i++) base += wc[i];
    int rank = __popcll(m & ((1ull << lane) - 1));
    if (n < NN) {
        int pos = base + rank;
        if (flag) comp[pos] = n;
        inv[n] = flag ? pos : -1;
    }
}

// f32 -> f16 weight conversion into MFMA FRAGMENT ORDER; block 304 = bq2 prep.
__global__ void k_cvtw(const float* __restrict__ W1, const float* __restrict__ W2,
                       const float* __restrict__ Wi, const float* __restrict__ Wh,
                       const float* __restrict__ Wq, const float* __restrict__ Wv,
                       const float* __restrict__ Wo, const float* __restrict__ mW1,
                       const float* __restrict__ mW2, const float* __restrict__ Wk,
                       const float* __restrict__ bq, const float* __restrict__ time_b,
                       _Float16* __restrict__ dst, float* __restrict__ bq2) {
    if (blockIdx.x == 304) {   // bq2[c] = bq[c] + Wq_right[c] . cos(time_b)
        __shared__ float cte[128];
        int t = threadIdx.x;
        if (t < 128) cte[t] = fast_cos(time_b[t]);
        __syncthreads();
        float acc = bq[t];
        #pragma unroll 4
        for (int d = 0; d < 128; d++)
            acc += Wq[(size_t)t * 256 + 128 + d] * cte[d];
        bq2[t] = acc;
        return;
    }
    int f = blockIdx.x * 256 + threadIdx.x;   // fragment id, 77824 total
    if (f >= 77824) return;
    const float* src; int dstoff, K, ldb, lf, tr = -1;
    if      (f < 16384) { src = W1;  dstoff = 0;      K = 512; ldb = 512; lf = f; }
    else if (f < 20480) { src = W2;  dstoff = 131072; K = 256; ldb = 256; lf = f - 16384; }
    else if (f < 26624) { src = Wi;  dstoff = 163840; K = 128; ldb = 128; lf = f - 20480; }
    else if (f < 32768) { src = Wh;  dstoff = 212992; K = 128; ldb = 128; lf = f - 26624; }
    else if (f < 36864) { src = Wq;  dstoff = 262144; K = 128; ldb = 256; lf = f - 32768; } // Wq left half
    else if (f < 43008) { src = Wv;  dstoff = 294912; K = 384; ldb = 384; lf = f - 36864; }
    else if (f < 49152) { src = Wv + 128 * 384; dstoff = 344064; K = 384; ldb = 384; lf = f - 43008; }
    else if (f < 57344) { src = Wo;  dstoff = 393216; K = 256; ldb = 256; lf = f - 49152; }
    else if (f < 63488) { src = mW1; dstoff = 458752; K = 384; ldb = 384; lf = f - 57344; }
    else if (f < 65536) { src = mW2; dstoff = 507904; K = 128; ldb = 128; lf = f - 63488; }
    else if (f < 71680) { src = Wk;  dstoff = 524288; K = 128; ldb = 0; lf = f - 65536; tr = 0; }
    else                { src = Wk;  dstoff = 573440; K = 128; ldb = 0; lf = f - 71680; tr = 1; }
    int KS = K >> 5;
    int cgrp = lf / (KS * 64);
    int rem  = lf - cgrp * (KS * 64);
    int ks = rem >> 6, lane = rem & 63;
    int kg = lane >> 4, arow = lane & 15;
    int col = cgrp * 16 + arow;
    int k0 = ks * 32 + kg * 8;
    f16x8 h;
    if (tr < 0) {
        const float* p = src + (size_t)col * ldb + k0;
        float4 a = *(const float4*)p;
        float4 b = *(const float4*)(p + 4);
        h[0] = (_Float16)a.x; h[1] = (_Float16)a.y; h[2] = (_Float16)a.z; h[3] = (_Float16)a.w;
        h[4] = (_Float16)b.x; h[5] = (_Float16)b.y; h[6] = (_Float16)b.z; h[7] = (_Float16)b.w;
    } else {
        #pragma unroll
        for (int e = 0; e < 8; e++)
            h[e] = (_Float16)Wk[(size_t)(tr * 128 + k0 + e) * 384 + col];
    }
    *(f16x8*)(dst + dstoff + (size_t)lf * 8) = h;
}

// ---------------- Stage 1: 64 rows/block, 512 threads / 8 waves (R12-exact) ----------------
// launch_bounds (512,2): LDS-capped at 2 blocks/CU; 2 waves/EU declaration keeps
// the full 128+ VGPR budget (R13 showed (512,6) forces VGPR=40 -> scratch spills).
__device__ __forceinline__ int SWA(int r, int byteofs) {
    return r * 1024 + (byteofs ^ ((r & 7) << 4));
}

__device__ __forceinline__ f16x8 ldw4(const _Float16* W, int cg, int ks, int lane) {
    return *(const f16x8*)(W + (((size_t)cg * 4 + ks) * 64 + lane) * 8);
}

__global__ __launch_bounds__(512, 2)
void k_stage1(const int* __restrict__ comp, const int* __restrict__ count,
              const int* __restrict__ lastpos,
              const int* __restrict__ msg_dst, const int* __restrict__ msg_eidx,
              const int* __restrict__ msg_t, const int* __restrict__ last_update,
              const float* __restrict__ memory, const float* __restrict__ edge_feats,
              const float* __restrict__ time_w, const float* __restrict__ time_b,
              const _Float16* __restrict__ W1h, const float* __restrict__ b1,
              const _Float16* __restrict__ W2h, const float* __restrict__ b2,
              const _Float16* __restrict__ Wih, const _Float16* __restrict__ Whh,
              const float* __restrict__ bi, const float* __restrict__ bh,
              _Float16* __restrict__ new_mem)
{
    __shared__ char rawb[64 * 1024];
    __shared__ int sn[64], sd[64], se[64];
    __shared__ float sdt[64];

    int cnt = *count;
    int r0 = blockIdx.x * 64;
    if (r0 >= cnt) return;
    int tid = threadIdx.x;

    if (tid < 64) {
        int rr = r0 + tid;
        int j = (rr < cnt) ? rr : r0;
        int n = comp[j];
        int idx = lastpos[n];
        sn[tid] = n;
        sd[tid] = msg_dst[idx];
        se[tid] = msg_eidx[idx];
        sdt[tid] = (float)(msg_t[idx] - last_update[n]);
    }
    __syncthreads();

    #pragma unroll
    for (int it = 0; it < 6; it++) {
        int gi = tid + it * 512;
        int r = gi / 48, g = gi - r * 48;
        const float* src;
        if (g < 16)      src = memory + (size_t)sn[r] * 128 + g * 8;
        else if (g < 32) src = memory + (size_t)sd[r] * 128 + (g - 16) * 8;
        else             src = edge_feats + (size_t)se[r] * 128 + (g - 32) * 8;
        float4 a = *(const float4*)src;
        float4 b = *(const float4*)(src + 4);
        f16x8 h;
        h[0] = (_Float16)a.x; h[1] = (_Float16)a.y; h[2] = (_Float16)a.z; h[3] = (_Float16)a.w;
        h[4] = (_Float16)b.x; h[5] = (_Float16)b.y; h[6] = (_Float16)b.z; h[7] = (_Float16)b.w;
        *(f16x8*)(rawb + SWA(r, g * 16)) = h;
    }
    #pragma unroll
    for (int it = 0; it < 2; it++) {
        int gi = tid + it * 512;
        int r = gi >> 4, g = gi & 15;
        int c = g * 8;
        float dt = sdt[r];
        float4 w0 = *(const float4*)(time_w + c);
        float4 w1 = *(const float4*)(time_w + c + 4);
        float4 t0 = *(const float4*)(time_b + c);
        float4 t1 = *(const float4*)(time_b + c + 4);
        f16x8 h;
        h[0] = (_Float16)tenc(dt, w0.x, t0.x); h[1] = (_Float16)tenc(dt, w0.y, t0.y);
        h[2] = (_Float16)tenc(dt, w0.z, t0.z); h[3] = (_Float16)tenc(dt, w0.w, t0.w);
        h[4] = (_Float16)tenc(dt, w1.x, t1.x); h[5] = (_Float16)tenc(dt, w1.y, t1.y);
        h[6] = (_Float16)tenc(dt, w1.z, t1.z); h[7] = (_Float16)tenc(dt, w1.w, t1.w);
        *(f16x8*)(rawb + SWA(r, (48 + g) * 16)) = h;
    }
    __syncthreads();

    int wv = tid >> 6, lane = tid & 63;
    int arow = lane & 15, kg = lane >> 4;

    f32x4 acc1[2][4];
    #pragma unroll
    for (int c = 0; c < 2; c++)
        #pragma unroll
        for (int rt = 0; rt < 4; rt++) acc1[c][rt] = z4();
    for (int ks = 0; ks < 16; ks++) {
        f16x8 a[4];
        #pragma unroll
        for (int rt = 0; rt < 4; rt++)
            a[rt] = *(const f16x8*)(rawb + SWA(rt * 16 + arow, ks * 64 + kg * 16));
        #pragma unroll
        for (int c = 0; c < 2; c++) {
            f16x8 b = *(const f16x8*)(W1h + (((size_t)(wv * 2 + c) * 16 + ks) * 64 + lane) * 8);
            #pragma unroll
            for (int rt = 0; rt < 4; rt++)
                acc1[c][rt] = MFMA16(a[rt], b, acc1[c][rt]);
        }
    }
    __syncthreads();

    #pragma unroll
    for (int c = 0; c < 2; c++) {
        int col = (wv * 2 + c) * 16 + arow;
        float bb = b1[col];
        #pragma unroll
        for (int rt = 0; rt < 4; rt++)
            #pragma unroll
            for (int rg = 0; rg < 4; rg++) {
                int row = rt * 16 + kg * 4 + rg;
                float v = fmaxf(acc1[c][rt][rg] + bb, 0.f);
                *(_Float16*)(rawb + SWA(row, 384 + col * 2)) = (_Float16)v;
            }
    }
    __syncthreads();

    f32x4 acc2[4];
    #pragma unroll
    for (int rt = 0; rt < 4; rt++) acc2[rt] = z4();
    for (int ks = 0; ks < 8; ks++) {
        f16x8 b = *(const f16x8*)(W2h + (((size_t)wv * 8 + ks) * 64 + lane) * 8);
        #pragma unroll
        for (int rt = 0; rt < 4; rt++) {
            f16x8 a = *(const f16x8*)(rawb + SWA(rt * 16 + arow, 384 + ks * 64 + kg * 16));
            acc2[rt] = MFMA16(a, b, acc2[rt]);
        }
    }
    __syncthreads();

    {
        int col = wv * 16 + arow;
        float bb = b2[col];
        #pragma unroll
        for (int rt = 0; rt < 4; rt++)
            #pragma unroll
            for (int rg = 0; rg < 4; rg++) {
                int row = rt * 16 + kg * 4 + rg;
                *(_Float16*)(rawb + SWA(row, 384 + col * 2)) =
                    (_Float16)(acc2[rt][rg] + bb);
            }
    }
    __syncthreads();

    f32x4 aR[4], aZ[4], aNi[4], aNh[4];
    #pragma unroll
    for (int rt = 0; rt < 4; rt++) { aR[rt] = z4(); aZ[rt] = z4(); aNi[rt] = z4(); aNh[rt] = z4(); }
    for (int ks = 0; ks < 4; ks++) {
        f16x8 bi_ = ldw4(Wih, wv, ks, lane);
        f16x8 bh_ = ldw4(Whh, wv, ks, lane);
        #pragma unroll
        for (int rt = 0; rt < 4; rt++) {
            f16x8 m = *(const f16x8*)(rawb + SWA(rt * 16 + arow, 384 + ks * 64 + kg * 16));
            f16x8 hh = *(const f16x8*)(rawb + SWA(rt * 16 + arow, ks * 64 + kg * 16));
            aR[rt] = MFMA16(m, bi_, aR[rt]);
            aR[rt] = MFMA16(hh, bh_, aR[rt]);
        }
    }
    for (int ks = 0; ks < 4; ks++) {
        f16x8 bi_ = ldw4(Wih, 8 + wv, ks, lane);
        f16x8 bh_ = ldw4(Whh, 8 + wv, ks, lane);
        #pragma unroll
        for (int rt = 0; rt < 4; rt++) {
            f16x8 m = *(const f16x8*)(rawb + SWA(rt * 16 + arow, 384 + ks * 64 + kg * 16));
            f16x8 hh = *(const f16x8*)(rawb + SWA(rt * 16 + arow, ks * 64 + kg * 16));
            aZ[rt] = MFMA16(m, bi_, aZ[rt]);
            aZ[rt] = MFMA16(hh, bh_, aZ[rt]);
        }
    }
    for (int ks = 0; ks < 4; ks++) {
        f16x8 bi_ = ldw4(Wih, 16 + wv, ks, lane);
        f16x8 bh_ = ldw4(Whh, 16 + wv, ks, lane);
        #pragma unroll
        for (int rt = 0; rt < 4; rt++) {
            f16x8 m = *(const f16x8*)(rawb + SWA(rt * 16 + arow, 384 + ks * 64 + kg * 16));
            f16x8 hh = *(const f16x8*)(rawb + SWA(rt * 16 + arow, ks * 64 + kg * 16));
            aNi[rt] = MFMA16(m, bi_, aNi[rt]);
            aNh[rt] = MFMA16(hh, bh_, aNh[rt]);
        }
    }

    {
        int col = wv * 16 + arow;
        float bir = bi[col],        bhr = bh[col];
        float biz = bi[128 + col],  bhz = bh[128 + col];
        float bin_ = bi[256 + col], bhn_ = bh[256 + col];
        #pragma unroll
        for (int rt = 0; rt < 4; rt++)
            #pragma unroll
            for (int rg = 0; rg < 4; rg++) {
                int row = rt * 16 + kg * 4 + rg;
                int rr = r0 + row;
                if (rr < cnt) {
                    float r_ = fsigm(aR[rt][rg] + bir + bhr);
                    float zg = fsigm(aZ[rt][rg] + biz + bhz);
                    float ng = ftanh(aNi[rt][rg] + bin_ + r_ * (aNh[rt][rg] + bhn_));
                    float om = (float)*(const _Float16*)(rawb + SWA(row, col * 2));
                    new_mem[(size_t)rr * 128 + col] = (_Float16)((1.f - zg) * ng + zg * om);
                }
            }
    }
}

// k_feat: feat[n] = (updated ? new_mem[inv[n]] : memory[n]) + node_feats[n], f16.
// Only for referenced nodes (mask).
__global__ __launch_bounds__(256)
void k_feat(const int* __restrict__ inv, const char* __restrict__ mask,
            const _Float16* __restrict__ new_mem,
            const float* __restrict__ memory, const float* __restrict__ node_feats,
            _Float16* __restrict__ feat)
{
    int idx = blockIdx.x * 256 + threadIdx.x;
    if (idx >= NN * 16) return;
    int n = idx >> 4, g = idx & 15;
    if (!mask[n]) return;
    int c = g * 8;
    int iv = inv[n];
    float4 n0 = *(const float4*)(node_feats + (size_t)n * 128 + c);
    float4 n1 = *(const float4*)(node_feats + (size_t)n * 128 + c + 4);
    f16x8 o;
    if (iv >= 0) {
        f16x8 mv = *(const f16x8*)(new_mem + (size_t)iv * 128 + c);
        o[0] = (_Float16)((float)mv[0] + n0.x); o[1] = (_Float16)((float)mv[1] + n0.y);
        o[2] = (_Float16)((float)mv[2] + n0.z); o[3] = (_Float16)((float)mv[3] + n0.w);
        o[4] = (_Float16)((float)mv[4] + n1.x); o[5] = (_Float16)((float)mv[5] + n1.y);
        o[6] = (_Float16)((float)mv[6] + n1.z); o[7] = (_Float16)((float)mv[7] + n1.w);
    } else {
        float4 m0 = *(const float4*)(memory + (size_t)n * 128 + c);
        float4 m1 = *(const float4*)(memory + (size_t)n * 128 + c + 4);
        o[0] = (_Float16)(m0.x + n0.x); o[1] = (_Float16)(m0.y + n0.y);
        o[2] = (_Float16)(m0.z + n0.z); o[3] = (_Float16)(m0.w + n0.w);
        o[4] = (_Float16)(m1.x + n1.x); o[5] = (_Float16)(m1.y + n1.y);
        o[6] = (_Float16)(m1.z + n1.z); o[7] = (_Float16)(m1.w + n1.w);
    }
    *(f16x8*)(feat + (size_t)n * 128 + c) = o;
}

// ---------------- Stage 2 (R12-exact) ----------------
__global__ __launch_bounds__(512, 2)
void k2b(const int* __restrict__ src_nodes, const int* __restrict__ dst_nodes,
         const int* __restrict__ neg_nodes, const _Float16* __restrict__ feat,
         const _Float16* __restrict__ WqLh, const float* __restrict__ bq2,
         const _Float16* __restrict__ Wkth,
         _Float16* __restrict__ sfeat, _Float16* __restrict__ qk_ws)
{
    __shared__ char lds[24 * 1024];    // [0,8K): sfeat tile; [8K,24K): q tile
    __shared__ int snode[32];
    int tid = threadIdx.x;
    int r0 = blockIdx.x * 32;

    if (tid < 32) {
        int q = r0 + tid;
        snode[tid] = (q < BB) ? src_nodes[q] : (q < 2 * BB) ? dst_nodes[q - BB] : neg_nodes[q - 2 * BB];
    }
    __syncthreads();

    {
        int r = tid >> 4, g = tid & 15;
        f16x8 v = *(const f16x8*)(feat + (size_t)snode[r] * 128 + g * 8);
        *(f16x8*)(&lds[r * 256 + ((g * 16) ^ ((r & 7) << 4))]) = v;
        *(f16x8*)(sfeat + (size_t)(r0 + r) * 128 + g * 8) = v;
    }
    __syncthreads();

    int wv = tid >> 6, lane = tid & 63;
    int arow = lane & 15, kg = lane >> 4;

    f32x4 acc[2][2];
    #pragma unroll
    for (int c = 0; c < 2; c++) { acc[c][0] = z4(); acc[c][1] = z4(); }
    for (int ks = 0; ks < 4; ks++) {
        f16x8 a0 = *(const f16x8*)(&lds[arow * 256 + ((ks * 64 + kg * 16) ^ ((arow & 7) << 4))]);
        f16x8 a1 = *(const f16x8*)(&lds[(16 + arow) * 256 + ((ks * 64 + kg * 16) ^ ((arow & 7) << 4))]);
        #pragma unroll
        for (int c = 0; c < 2; c++) {
            f16x8 b = *(const f16x8*)(WqLh + (((size_t)(wv * 2 + c) * 4 + ks) * 64 + lane) * 8);
            acc[c][0] = MFMA16(a0, b, acc[c][0]);
            acc[c][1] = MFMA16(a1, b, acc[c][1]);
        }
    }
    #pragma unroll
    for (int c = 0; c < 2; c++) {
        int col = (wv * 2 + c) * 16 + arow;
        float bb = bq2[col];
        #pragma unroll
        for (int rt = 0; rt < 2; rt++)
            #pragma unroll
            for (int rg = 0; rg < 4; rg++) {
                int row = rt * 16 + kg * 4 + rg;
                *(_Float16*)(&lds[8192 + row * 512 + ((col * 2) ^ ((row & 7) << 4))]) =
                    (_Float16)(acc[c][rt][rg] + bb);
            }
    }
    __syncthreads();

    int h = wv >> 2;
    f32x4 acc2[6][2];
    #pragma unroll
    for (int c = 0; c < 6; c++) { acc2[c][0] = z4(); acc2[c][1] = z4(); }
    for (int ks = 0; ks < 4; ks++) {
        f16x8 a0 = *(const f16x8*)(&lds[8192 + arow * 512 +
                    ((h * 256 + ks * 64 + kg * 16) ^ ((arow & 7) << 4))]);
        f16x8 a1 = *(const f16x8*)(&lds[8192 + (16 + arow) * 512 +
                    ((h * 256 + ks * 64 + kg * 16) ^ ((arow & 7) << 4))]);
        #pragma unroll
        for (int c = 0; c < 6; c++) {
            int cgh = (wv & 3) * 6 + c;
            f16x8 b = *(const f16x8*)(Wkth + (size_t)h * 49152 +
                       (((size_t)cgh * 4 + ks) * 64 + lane) * 8);
            acc2[c][0] = MFMA16(a0, b, acc2[c][0]);
            acc2[c][1] = MFMA16(a1, b, acc2[c][1]);
        }
    }
    #pragma unroll
    for (int c = 0; c < 6; c++) {
        int cgh = (wv & 3) * 6 + c;
        int col = h * 384 + cgh * 16 + arow;
        #pragma unroll
        for (int rt = 0; rt < 2; rt++)
            #pragma unroll
            for (int rg = 0; rg < 4; rg++) {
                int row = rt * 16 + kg * 4 + rg;
                qk_ws[(size_t)(r0 + row) * 768 + col] = (_Float16)acc2[c][rt][rg];
            }
    }
}

// generic 32-row-tile MFMA GEMM, fragment-ordered B (used for Wv fold only).
template<int KD, int NFRAG, bool RELU>
__global__ __launch_bounds__(256, 4)
void k_gemm(const _Float16* __restrict__ A, int lda, int a_ys,
            const _Float16* __restrict__ B, int b_ys,
            const float* __restrict__ bias, int bias_ys,
            _Float16* __restrict__ C, int ldc, int c_ys,
            float* __restrict__ C32,
            const int* __restrict__ rowmask)
{
    constexpr int ROWB = KD * 2;
    __shared__ char As[32 * ROWB];
    int tid = threadIdx.x;
    int r0 = blockIdx.x * 32;
    int aoff = blockIdx.y * a_ys;
    const _Float16* Bp = B + (size_t)blockIdx.y * b_ys;
    int coff = blockIdx.y * c_ys;

    #pragma unroll
    for (int t = 0; t < (32 * KD / 8) / 256; t++) {
        int gi = tid + t * 256;
        int r = gi / (KD / 8), g = gi % (KD / 8);
        f16x8 v = *(const f16x8*)(A + (size_t)(r0 + r) * lda + aoff + g * 8);
        *(f16x8*)(&As[r * ROWB + ((g * 16) ^ ((r & 7) << 4))]) = v;
    }
    __syncthreads();

    int wv = tid >> 6, lane = tid & 63;
    int arow = lane & 15, kg = lane >> 4;
    f32x4 acc[NFRAG][2];
    #pragma unroll
    for (int c = 0; c < NFRAG; c++) { acc[c][0] = z4(); acc[c][1] = z4(); }

    #pragma unroll
    for (int ks = 0; ks < KD / 32; ks++) {
        f16x8 a0 = *(const f16x8*)(&As[arow * ROWB + ((ks * 64 + kg * 16) ^ ((arow & 7) << 4))]);
        f16x8 a1 = *(const f16x8*)(&As[(16 + arow) * ROWB + ((ks * 64 + kg * 16) ^ ((arow & 7) << 4))]);
        #pragma unroll
        for (int c = 0; c < NFRAG; c++) {
            f16x8 b = *(const f16x8*)(Bp +
                (((size_t)(wv * NFRAG + c) * (KD / 32) + ks) * 64 + lane) * 8);
            acc[c][0] = MFMA16(a0, b, acc[c][0]);
            acc[c][1] = MFMA16(a1, b, acc[c][1]);
        }
    }

    #pragma unroll
    for (int c = 0; c < NFRAG; c++) {
        int cg = (wv * NFRAG + c) * 16 + arow;
        float bb = bias ? bias[blockIdx.y * bias_ys + cg] : 0.f;
        #pragma unroll
        for (int rt = 0; rt < 2; rt++)
            #pragma unroll
            for (int rg = 0; rg < 4; rg++) {
                int grow = r0 + rt * 16 + kg * 4 + rg;
                float v = acc[c][rt][rg] + bb;
                if (RELU) v = fmaxf(v, 0.f);
                if (rowmask && rowmask[grow]) v = 0.f;
                if (C)   C[(size_t)grow * ldc + coff + cg] = (_Float16)v;
                if (C32) C32[(size_t)grow * ldc + coff + cg] = v;
            }
    }
}

// k2d: attention core (R12-exact).
__global__ __launch_bounds__(256)
void k2d(const int* __restrict__ neighbors, const int* __restrict__ nb_eidx,
         const int* __restrict__ nb_et, const int* __restrict__ edge_times,
         const _Float16* __restrict__ feat,
         const float* __restrict__ edge_feats, const float* __restrict__ time_w,
         const float* __restrict__ time_b,
         _Float16* __restrict__ qk_wsum, int* __restrict__ allm)
{
    int tid = threadIdx.x;
    int qi = blockIdx.x * 4 + (tid >> 6);
    int lane = tid & 63;
    int h = lane >> 5, l32 = lane & 31;
    int c0 = l32 * 4;

    float4 tw = *(const float4*)(time_w + c0);
    float4 tb = *(const float4*)(time_b + c0);

    const _Float16* qkp = qk_wsum + (size_t)qi * 768 + h * 384;
    f16x4 t0 = *(const f16x4*)(qkp + c0);
    f16x4 t1 = *(const f16x4*)(qkp + 128 + c0);
    f16x4 t2 = *(const f16x4*)(qkp + 256 + c0);
    float qk0[4], qk1[4], qk2[4];
    #pragma unroll
    for (int t = 0; t < 4; t++) { qk0[t] = (float)t0[t]; qk1[t] = (float)t1[t]; qk2[t] = (float)t2[t]; }

    float ts = (float)edge_times[qi & (BB - 1)];
    float m_run = -3.0e38f, l_run = 0.f;
    float w0[4] = {0,0,0,0}, w1[4] = {0,0,0,0}, w2[4] = {0,0,0,0};
    int anyv = 0;
    const float inv_sqrt = 0.08838834764831845f;

    int base = qi * KK;
    int nb_c = neighbors[base];
    int ei_c = nb_eidx[base];
    int et_c = nb_et[base];
    f16x4 fv;
    float4 ef;
    {
        fv = *(const f16x4*)(feat + (size_t)nb_c * 128 + c0);
        ef = *(const float4*)(edge_feats + (size_t)ei_c * 128 + c0);
    }

    for (int j = 0; j < KK; j++) {
        int nb_n = 0, ei_n = 0, et_n = 0;
        f16x4 fv_n = {0,0,0,0};
        float4 ef_n = {0,0,0,0};
        if (j + 1 < KK) {
            nb_n = neighbors[base + j + 1];
            ei_n = nb_eidx[base + j + 1];
            et_n = nb_et[base + j + 1];
            fv_n = *(const f16x4*)(feat + (size_t)nb_n * 128 + c0);
            ef_n = *(const float4*)(edge_feats + (size_t)ei_n * 128 + c0);
        }

        float dtf = ts - (float)et_c;
        anyv |= (nb_c != 0);
        float k0[4] = { (float)fv[0], (float)fv[1], (float)fv[2], (float)fv[3] };
        float k1[4] = { tenc(dtf, tw.x, tb.x), tenc(dtf, tw.y, tb.y),
                        tenc(dtf, tw.z, tb.z), tenc(dtf, tw.w, tb.w) };
        float k2[4] = { ef.x, ef.y, ef.z, ef.w };

        float sp = 0.f;
        #pragma unroll
        for (int t = 0; t < 4; t++)
            sp += qk0[t] * k0[t] + qk1[t] * k1[t] + qk2[t] * k2[t];
        sp += __shfl_xor(sp, 1, 32);
        sp += __shfl_xor(sp, 2, 32);
        sp += __shfl_xor(sp, 4, 32);
        sp += __shfl_xor(sp, 8, 32);
        sp += __shfl_xor(sp, 16, 32);

        float s = sp * inv_sqrt;
        if (nb_c == 0) s = -1e9f;
        float m_new = fmaxf(m_run, s);
        float sc = __expf(m_run - m_new);
        float p = __expf(s - m_new);
        l_run = l_run * sc + p;
        #pragma unroll
        for (int t = 0; t < 4; t++) {
            w0[t] = w0[t] * sc + p * k0[t];
            w1[t] = w1[t] * sc + p * k1[t];
            w2[t] = w2[t] * sc + p * k2[t];
        }
        m_run = m_new;

        nb_c = nb_n; ei_c = ei_n; et_c = et_n;
        fv = fv_n; ef = ef_n;
    }

    float linv = __builtin_amdgcn_rcpf(l_run);
    _Float16* wp = qk_wsum + (size_t)qi * 768 + h * 384;
    f16x4 o0, o1, o2;
    #pragma unroll
    for (int t = 0; t < 4; t++) {
        o0[t] = (_Float16)(w0[t] * linv);
        o1[t] = (_Float16)(w1[t] * linv);
        o2[t] = (_Float16)(w2[t] * linv);
    }
    *(f16x4*)(wp + c0) = o0;
    *(f16x4*)(wp + 128 + c0) = o1;
    *(f16x4*)(wp + 256 + c0) = o2;
    if (lane == 0) allm[qi] = anyv ? 0 : 1;
}

// k2t2: fused tail (R12-exact).
__global__ __launch_bounds__(256, 2)
void k2t2(const _Float16* __restrict__ ctx, const _Float16* __restrict__ sfeat,
          const _Float16* __restrict__ Woh, const float* __restrict__ bo,
          const _Float16* __restrict__ mW1h, const float* __restrict__ mb1,
          const _Float16* __restrict__ mW2h, const float* __restrict__ mb2,
          const int* __restrict__ allm, float* __restrict__ out)
{
    __shared__ char lds[48 * 1024];
    int tid = threadIdx.x;
    int r0 = blockIdx.x * 32;

    #pragma unroll
    for (int t = 0; t < 4; t++) {
        int gi = tid + t * 256;
        int r = gi >> 5, g = gi & 31;
        f16x8 v = *(const f16x8*)(ctx + (size_t)(r0 + r) * 256 + g * 8);
        *(f16x8*)(&lds[r * 512 + ((g * 16) ^ ((r & 7) << 4))]) = v;
    }
    __syncthreads();

    int wv = tid >> 6, lane = tid & 63;
    int arow = lane & 15, kg = lane >> 4;

    f32x4 acc[4][2];
    #pragma unroll
    for (int c = 0; c < 4; c++) { acc[c][0] = z4(); acc[c][1] = z4(); }
    for (int ks = 0; ks < 8; ks++) {
        f16x8 a0 = *(const f16x8*)(&lds[arow * 512 + ((ks * 64 + kg * 16) ^ ((arow & 7) << 4))]);
        f16x8 a1 = *(const f16x8*)(&lds[(16 + arow) * 512 + ((ks * 64 + kg * 16) ^ ((arow & 7) << 4))]);
        #pragma unroll
        for (int c = 0; c < 4; c++) {
            f16x8 b = *(const f16x8*)(Woh + (((size_t)(wv * 4 + c) * 8 + ks) * 64 + lane) * 8);
            acc[c][0] = MFMA16(a0, b, acc[c][0]);
            acc[c][1] = MFMA16(a1, b, acc[c][1]);
        }
    }
    #pragma unroll
    for (int c = 0; c < 4; c++) {
        int col = (wv * 4 + c) * 16 + arow;
        float bb = bo[col];
        #pragma unroll
        for (int rt = 0; rt < 2; rt++)
            #pragma unroll
            for (int rg = 0; rg < 4; rg++) {
                int row = rt * 16 + kg * 4 + rg;
                float v = allm[r0 + row] ? 0.f : (acc[c][rt][rg] + bb);
                *(_Float16*)(&lds[16384 + row * 768 + ((col * 2) ^ ((row & 7) << 4))]) = (_Float16)v;
            }
    }
    #pragma unroll
    for (int t = 0; t < 2; t++) {
        int gi = tid + t * 256;
        int r = gi >> 4, g = gi & 15;
        f16x8 v = *(const f16x8*)(sfeat + (size_t)(r0 + r) * 128 + g * 8);
        *(f16x8*)(&lds[16384 + r * 768 + ((512 + g * 16) ^ ((r & 7) << 4))]) = v;
    }
    __syncthreads();

    f32x4 acc2[2][2];
    #pragma unroll
    for (int c = 0; c < 2; c++) { acc2[c][0] = z4(); acc2[c][1] = z4(); }
    for (int ks = 0; ks < 12; ks++) {
        f16x8 a0 = *(const f16x8*)(&lds[16384 + arow * 768 + ((ks * 64 + kg * 16) ^ ((arow & 7) << 4))]);
        f16x8 a1 = *(const f16x8*)(&lds[16384 + (16 + arow) * 768 + ((ks * 64 + kg * 16) ^ ((arow & 7) << 4))]);
        #pragma unroll
        for (int c = 0; c < 2; c++) {
            f16x8 b = *(const f16x8*)(mW1h + (((size_t)(wv * 2 + c) * 12 + ks) * 64 + lane) * 8);
            acc2[c][0] = MFMA16(a0, b, acc2[c][0]);
            acc2[c][1] = MFMA16(a1, b, acc2[c][1]);
        }
    }
    #pragma unroll
    for (int c = 0; c < 2; c++) {
        int col = (wv * 2 + c) * 16 + arow;
        float bb = mb1[col];
        #pragma unroll
        for (int rt = 0; rt < 2; rt++)
            #pragma unroll
            for (int rg = 0; rg < 4; rg++) {
                int row = rt * 16 + kg * 4 + rg;
                float v = fmaxf(acc2[c][rt][rg] + bb, 0.f);
                *(_Float16*)(&lds[40960 + row * 256 + ((col * 2) ^ ((row & 7) << 4))]) = (_Float16)v;
            }
    }
    __syncthreads();

    f32x4 acc3[2][2];
    #pragma unroll
    for (int c = 0; c < 2; c++) { acc3[c][0] = z4(); acc3[c][1] = z4(); }
    for (int ks = 0; ks < 4; ks++) {
        f16x8 a0 = *(const f16x8*)(&lds[40960 + arow * 256 + ((ks * 64 + kg * 16) ^ ((arow & 7) << 4))]);
        f16x8 a1 = *(const f16x8*)(&lds[40960 + (16 + arow) * 256 + ((ks * 64 + kg * 16) ^ ((arow & 7) << 4))]);
        #pragma unroll
        for (int c = 0; c < 2; c++) {
            f16x8 b = *(const f16x8*)(mW2h + (((size_t)(wv * 2 + c) * 4 + ks) * 64 + lane) * 8);
            acc3[c][0] = MFMA16(a0, b, acc3[c][0]);
            acc3[c][1] = MFMA16(a1, b, acc3[c][1]);
        }
    }
    #pragma unroll
    for (int c = 0; c < 2; c++) {
        int col = (wv * 2 + c) * 16 + arow;
        float bb = mb2[col];
        #pragma unroll
        for (int rt = 0; rt < 2; rt++)
            #pragma unroll
            for (int rg = 0; rg < 4; rg++) {
                int row = rt * 16 + kg * 4 + rg;
                out[(size_t)(r0 + row) * 128 + col] = acc3[c][rt][rg] + bb;
            }
    }
}

extern "C" void kernel_launch(void* const* d_in, const int* in_sizes, int n_in,
                              void* d_out, int out_size, void* d_ws, size_t ws_size,
                              hipStream_t stream) {
    (void)in_sizes; (void)n_in; (void)out_size; (void)ws_size;
    const int* src_nodes  = (const int*)d_in[0];
    const int* dst_nodes  = (const int*)d_in[1];
    const int* neg_nodes  = (const int*)d_in[2];
    const int* edge_times = (const int*)d_in[3];
    const int* neighbors  = (const int*)d_in[4];
    const int* nb_eidx    = (const int*)d_in[5];
    const int* nb_et      = (const int*)d_in[6];
    const int* msg_src    = (const int*)d_in[7];
    const int* msg_dst    = (const int*)d_in[8];
    const int* msg_eidx   = (const int*)d_in[9];
    const int* msg_t      = (const int*)d_in[10];
    const int* last_update= (const int*)d_in[11];
    const float* node_feats = (const float*)d_in[12];
    const float* edge_feats = (const float*)d_in[13];
    const float* memory     = (const float*)d_in[14];
    const float* time_w = (const float*)d_in[15];
    const float* time_b = (const float*)d_in[16];
    const float* W1 = (const float*)d_in[17];
    const float* b1 = (const float*)d_in[18];
    const float* W2 = (const float*)d_in[19];
    const float* b2 = (const float*)d_in[20];
    const float* gWi = (const float*)d_in[21];
    const float* gWh = (const float*)d_in[22];
    const float* gbi = (const float*)d_in[23];
    const float* gbh = (const float*)d_in[24];
    const float* Wq = (const float*)d_in[25];
    const float* bq = (const float*)d_in[26];
    const float* Wk = (const float*)d_in[27];
    const float* bk = (const float*)d_in[28];
    const float* Wv = (const float*)d_in[29];
    const float* bv = (const float*)d_in[30];
    const float* Wo = (const float*)d_in[31];
    const float* bo = (const float*)d_in[32];
    const float* mW1 = (const float*)d_in[33];
    const float* mb1 = (const float*)d_in[34];
    const float* mW2 = (const float*)d_in[35];
    const float* mb2 = (const float*)d_in[36];
    float* out = (float*)d_out;
    (void)bk;

    char* w = (char*)d_ws;
    int* lastpos = (int*)w;
    int* inv  = lastpos + NN;
    int* comp = inv + NN;
    int* count = comp + NN;
    int* bcnt = count + 1;
    int* boff = bcnt + NBLK;
    char* mask = (char*)(boff + NBLK);                // NN bytes
    size_t off = ((size_t)(3 * NN + 1 + 2 * NBLK) * 4 + NN + 255) & ~(size_t)255;
    _Float16* new_mem = (_Float16*)(w + off);         // MM*128 f16
    size_t foff = off + (size_t)MM * 128 * 2;
    _Float16* feat = (_Float16*)(w + foff);           // NN*128 f16
    size_t woff = foff + (size_t)NN * 128 * 2;

    _Float16* Hpool = (_Float16*)(w + woff);          // 622592 f16, fragment order
    _Float16* W1h  = Hpool;
    _Float16* W2h  = Hpool + 131072;
    _Float16* Wih  = Hpool + 163840;
    _Float16* Whh  = Hpool + 212992;
    _Float16* WqLh = Hpool + 262144;
    _Float16* Wvh  = Hpool + 294912;
    _Float16* Woh  = Hpool + 393216;
    _Float16* mW1h = Hpool + 458752;
    _Float16* mW2h = Hpool + 507904;
    _Float16* Wkth = Hpool + 524288;
    float* bq2 = (float*)(Hpool + 622592);            // 256 f32
    size_t boff2 = woff + (size_t)622592 * 2 + 1024;

    _Float16* ctx   = (_Float16*)(w + boff2);         // Q3*256
    _Float16* qk_ws = ctx + (size_t)Q3 * 256;         // Q3*768
    _Float16* sfeat = qk_ws + (size_t)Q3 * 768;       // Q3*128
    int* allm       = (int*)(sfeat + (size_t)Q3 * 128);

    k_init<<<dim3(NBLK), dim3(256), 0, stream>>>(lastpos, mask);
    k_scatter<<<dim3((MM + 255) / 256), dim3(256), 0, stream>>>(msg_src, lastpos);
    k_mark<<<dim3((Q3 + Q3 * KK + 255) / 256), dim3(256), 0, stream>>>(
        src_nodes, dst_nodes, neg_nodes, neighbors, mask);
    k_count<<<dim3(NBLK), dim3(256), 0, stream>>>(lastpos, bcnt);
    k_scan<<<dim3(1), dim3(256), 0, stream>>>(bcnt, boff, count);
    k_fill<<<dim3(NBLK), dim3(256), 0, stream>>>(lastpos, boff, comp, inv);
    k_cvtw<<<dim3(305), dim3(256), 0, stream>>>(
        W1, W2, gWi, gWh, Wq, Wv, Wo, mW1, mW2, Wk, bq, time_b, Hpool, bq2);
    k_stage1<<<dim3((MM + 63) / 64), dim3(512), 0, stream>>>(
        comp, count, lastpos, msg_dst, msg_eidx, msg_t, last_update,
        memory, edge_feats, time_w, time_b,
        W1h, b1, W2h, b2, Wih, Whh, gbi, gbh, new_mem);
    k_feat<<<dim3(NN * 16 / 256), dim3(256), 0, stream>>>(
        inv, mask, new_mem, memory, node_feats, feat);

    k2b<<<dim3(Q3 / 32), dim3(512), 0, stream>>>(
        src_nodes, dst_nodes, neg_nodes, feat, WqLh, bq2, Wkth, sfeat, qk_ws);
    k2d<<<dim3(Q3 / 4), dim3(256), 0, stream>>>(
        neighbors, nb_eidx, nb_et, edge_times, feat,
        edge_feats, time_w, time_b, qk_ws, allm);
    k_gemm<384, 2, false><<<dim3(Q3 / 32, 2), dim3(256), 0, stream>>>(
        qk_ws, 768, 384, Wvh, 49152, bv, 128, ctx, 256, 128, nullptr, nullptr);
    k2t2<<<dim3(Q3 / 32), dim3(256), 0, stream>>>(
        ctx, sfeat, Woh, bo, mW1h, mb1, mW2h, mb2, allm, out);
}

// Round 16
// 255.450 us; speedup vs baseline: 1.3183x; 1.1027x over previous
//
#include <hip/hip_runtime.h>
#include <math.h>

#define NN 200000
#define EEDGE 500000
#define BB 4096
#define KK 20
#define MM 100000
#define Q3 (3*BB)
#define NBLK ((NN + 255) / 256)

typedef _Float16 __attribute__((ext_vector_type(8))) f16x8;
typedef _Float16 __attribute__((ext_vector_type(4))) f16x4;
typedef float __attribute__((ext_vector_type(4))) f32x4;

#define MFMA16(a,b,c) __builtin_amdgcn_mfma_f32_16x16x32_f16(a,b,c,0,0,0)

// cos(a) for |a| up to ~1e7: f64 range-reduction to revolutions + v_cos_f32.
__device__ __forceinline__ float fast_cos(float a) {
    double ad = (double)a * 0.15915494309189535;   // 1/(2*pi)
    double fr = ad - floor(ad);                    // [0,1) revolutions
    return __builtin_amdgcn_cosf((float)fr);       // cos(2*pi*x)
}

// time encoding matching numpy's f32 arg rounding — NO fma contraction.
__device__ __forceinline__ float tenc(float dt, float w, float b) {
    float p = __fmul_rn(dt, w);
    float a = __fadd_rn(p, b);
    return fast_cos(a);
}

__device__ __forceinline__ float fsigm(float x) {
    return __builtin_amdgcn_rcpf(1.f + __expf(-x));
}
__device__ __forceinline__ float ftanh(float x) {
    return 1.f - 2.f * __builtin_amdgcn_rcpf(1.f + __expf(2.f * x));
}

__device__ __forceinline__ f32x4 z4() {
    f32x4 v; v[0] = 0.f; v[1] = 0.f; v[2] = 0.f; v[3] = 0.f; return v;
}

__global__ void k_init(int* lastpos, char* mask) {
    int i = blockIdx.x * 256 + threadIdx.x;
    if (i < NN) { lastpos[i] = -1; mask[i] = 0; }
}

__global__ void k_scatter(const int* __restrict__ msg_src, int* __restrict__ lastpos) {
    int i = blockIdx.x * 256 + threadIdx.x;
    if (i < MM) atomicMax(&lastpos[msg_src[i]], i);
}

// mark nodes whose feat row is actually read (query nodes + all neighbors)
__global__ void k_mark(const int* __restrict__ src_nodes, const int* __restrict__ dst_nodes,
                       const int* __restrict__ neg_nodes, const int* __restrict__ neighbors,
                       char* __restrict__ mask) {
    int i = blockIdx.x * 256 + threadIdx.x;
    if (i < Q3) {
        int node = (i < BB) ? src_nodes[i] : (i < 2 * BB) ? dst_nodes[i - BB] : neg_nodes[i - 2 * BB];
        mask[node] = 1;
    } else {
        int e = i - Q3;
        if (e < Q3 * KK) mask[neighbors[e]] = 1;
    }
}

// ordered (sorted-by-node) compaction: count -> scan -> fill (R9-proven)
__global__ void k_count(const int* __restrict__ lastpos, int* __restrict__ bcnt) {
    int n = blockIdx.x * 256 + threadIdx.x;
    int flag = (n < NN && lastpos[n] >= 0) ? 1 : 0;
    unsigned long long m = __ballot(flag != 0);
    __shared__ int wc[4];
    int wave = threadIdx.x >> 6, lane = threadIdx.x & 63;
    if (lane == 0) wc[wave] = __popcll(m);
    __syncthreads();
    if (threadIdx.x == 0) bcnt[blockIdx.x] = wc[0] + wc[1] + wc[2] + wc[3];
}

__global__ void k_scan(const int* __restrict__ bcnt, int* __restrict__ boff,
                       int* __restrict__ count) {
    __shared__ int s[NBLK];
    int t = threadIdx.x;
    for (int i = t; i < NBLK; i += 256) s[i] = bcnt[i];
    __syncthreads();
    if (t == 0) {
        int acc = 0;
        for (int i = 0; i < NBLK; i++) { int v = s[i]; s[i] = acc; acc += v; }
        *count = acc;
    }
    __syncthreads();
    for (int i = t; i < NBLK; i += 256) boff[i] = s[i];
}

// fill also initializes inv (-1 for non-message nodes)
__global__ void k_fill(const int* __restrict__ lastpos, const int* __restrict__ boff,
                       int* __restrict__ comp, int* __restrict__ inv) {
    int n = blockIdx.x * 256 + threadIdx.x;
    int flag = (n < NN && lastpos[n] >= 0) ? 1 : 0;
    unsigned long long m = __ballot(flag != 0);
    __shared__ int wc[4];
    int wave = threadIdx.x >> 6, lane = threadIdx.x & 63;
    if (lane == 0) wc[wave] = __popcll(m);
    __syncthreads();
    int base = boff[blockIdx.x];
    for (int i = 0; i < wave; i++) base += wc[i];
    int rank = __popcll(m & ((1ull << lane) - 1));
    if (n < NN) {
        int pos = base + rank;
        if (flag) comp[pos] = n;
        inv[n] = flag ? pos : -1;
    }
}

// f32 -> f16 weight conversion into MFMA FRAGMENT ORDER; block 304 = bq2 prep.
__global__ void k_cvtw(const float* __restrict__ W1, const float* __restrict__ W2,
                       const float* __restrict__ Wi, const float* __restrict__ Wh,
                       const float* __restrict__ Wq, const float* __restrict__ Wv,
                       const float* __restrict__ Wo, const float* __restrict__ mW1,
                       const float* __restrict__ mW2, const float* __restrict__ Wk,
                       const float* __restrict__ bq, const float* __restrict__ time_b,
                       _Float16* __restrict__ dst, float* __restrict__ bq2) {
    if (blockIdx.x == 304) {   // bq2[c] = bq[c] + Wq_right[c] . cos(time_b)
        __shared__ float cte[128];
        int t = threadIdx.x;
        if (t < 128) cte[t] = fast_cos(time_b[t]);
        __syncthreads();
        float acc = bq[t];
        #pragma unroll 4
        for (int d = 0; d < 128; d++)
            acc += Wq[(size_t)t * 256 + 128 + d] * cte[d];
        bq2[t] = acc;
        return;
    }
    int f = blockIdx.x * 256 + threadIdx.x;   // fragment id, 77824 total
    if (f >= 77824) return;
    const float* src; int dstoff, K, ldb, lf, tr = -1;
    if      (f < 16384) { src = W1;  dstoff = 0;      K = 512; ldb = 512; lf = f; }
    else if (f < 20480) { src = W2;  dstoff = 131072; K = 256; ldb = 256; lf = f - 16384; }
    else if (f < 26624) { src = Wi;  dstoff = 163840; K = 128; ldb = 128; lf = f - 20480; }
    else if (f < 32768) { src = Wh;  dstoff = 212992; K = 128; ldb = 128; lf = f - 26624; }
    else if (f < 36864) { src = Wq;  dstoff = 262144; K = 128; ldb = 256; lf = f - 32768; } // Wq left half
    else if (f < 43008) { src = Wv;  dstoff = 294912; K = 384; ldb = 384; lf = f - 36864; }
    else if (f < 49152) { src = Wv + 128 * 384; dstoff = 344064; K = 384; ldb = 384; lf = f - 43008; }
    else if (f < 57344) { src = Wo;  dstoff = 393216; K = 256; ldb = 256; lf = f - 49152; }
    else if (f < 63488) { src = mW1; dstoff = 458752; K = 384; ldb = 384; lf = f - 57344; }
    else if (f < 65536) { src = mW2; dstoff = 507904; K = 128; ldb = 128; lf = f - 63488; }
    else if (f < 71680) { src = Wk;  dstoff = 524288; K = 128; ldb = 0; lf = f - 65536; tr = 0; }
    else                { src = Wk;  dstoff = 573440; K = 128; ldb = 0; lf = f - 71680; tr = 1; }
    int KS = K >> 5;
    int cgrp = lf / (KS * 64);
    int rem  = lf - cgrp * (KS * 64);
    int ks = rem >> 6, lane = rem & 63;
    int kg = lane >> 4, arow = lane & 15;
    int col = cgrp * 16 + arow;
    int k0 = ks * 32 + kg * 8;
    f16x8 h;
    if (tr < 0) {
        const float* p = src + (size_t)col * ldb + k0;
        f32x4 a = *(const f32x4*)p;
        f32x4 b = *(const f32x4*)(p + 4);
        h[0] = (_Float16)a[0]; h[1] = (_Float16)a[1]; h[2] = (_Float16)a[2]; h[3] = (_Float16)a[3];
        h[4] = (_Float16)b[0]; h[5] = (_Float16)b[1]; h[6] = (_Float16)b[2]; h[7] = (_Float16)b[3];
    } else {
        #pragma unroll
        for (int e = 0; e < 8; e++)
            h[e] = (_Float16)Wk[(size_t)(tr * 128 + k0 + e) * 384 + col];
    }
    *(f16x8*)(dst + dstoff + (size_t)lf * 8) = h;
}

// ---------------- Stage 1: 64 rows/block, 512 threads / 8 waves ----------------
// (512,2): LDS-capped at 2 blocks/CU; full VGPR budget (R13: (512,6) spilled).
// Gather loads are NON-TEMPORAL (clang ext-vector f32x4): read-once rows must
// not evict the L2-resident weight stream (R5/R13 FETCH ~2x expected).
__device__ __forceinline__ int SWA(int r, int byteofs) {
    return r * 1024 + (byteofs ^ ((r & 7) << 4));
}

__device__ __forceinline__ f16x8 ldw4(const _Float16* W, int cg, int ks, int lane) {
    return *(const f16x8*)(W + (((size_t)cg * 4 + ks) * 64 + lane) * 8);
}

__global__ __launch_bounds__(512, 2)
void k_stage1(const int* __restrict__ comp, const int* __restrict__ count,
              const int* __restrict__ lastpos,
              const int* __restrict__ msg_dst, const int* __restrict__ msg_eidx,
              const int* __restrict__ msg_t, const int* __restrict__ last_update,
              const float* __restrict__ memory, const float* __restrict__ edge_feats,
              const float* __restrict__ time_w, const float* __restrict__ time_b,
              const _Float16* __restrict__ W1h, const float* __restrict__ b1,
              const _Float16* __restrict__ W2h, const float* __restrict__ b2,
              const _Float16* __restrict__ Wih, const _Float16* __restrict__ Whh,
              const float* __restrict__ bi, const float* __restrict__ bh,
              _Float16* __restrict__ new_mem)
{
    __shared__ char rawb[64 * 1024];
    __shared__ int sn[64], sd[64], se[64];
    __shared__ float sdt[64];

    int cnt = *count;
    int r0 = blockIdx.x * 64;
    if (r0 >= cnt) return;
    int tid = threadIdx.x;

    if (tid < 64) {
        int rr = r0 + tid;
        int j = (rr < cnt) ? rr : r0;
        int n = comp[j];
        int idx = lastpos[n];
        sn[tid] = n;
        sd[tid] = msg_dst[idx];
        se[tid] = msg_eidx[idx];
        sdt[tid] = (float)(msg_t[idx] - last_update[n]);
    }
    __syncthreads();

    #pragma unroll
    for (int it = 0; it < 6; it++) {
        int gi = tid + it * 512;
        int r = gi / 48, g = gi - r * 48;
        const float* src;
        if (g < 16)      src = memory + (size_t)sn[r] * 128 + g * 8;
        else if (g < 32) src = memory + (size_t)sd[r] * 128 + (g - 16) * 8;
        else             src = edge_feats + (size_t)se[r] * 128 + (g - 32) * 8;
        f32x4 a = __builtin_nontemporal_load((const f32x4*)src);
        f32x4 b = __builtin_nontemporal_load((const f32x4*)(src + 4));
        f16x8 h;
        h[0] = (_Float16)a[0]; h[1] = (_Float16)a[1]; h[2] = (_Float16)a[2]; h[3] = (_Float16)a[3];
        h[4] = (_Float16)b[0]; h[5] = (_Float16)b[1]; h[6] = (_Float16)b[2]; h[7] = (_Float16)b[3];
        *(f16x8*)(rawb + SWA(r, g * 16)) = h;
    }
    #pragma unroll
    for (int it = 0; it < 2; it++) {
        int gi = tid + it * 512;
        int r = gi >> 4, g = gi & 15;
        int c = g * 8;
        float dt = sdt[r];
        f32x4 w0 = *(const f32x4*)(time_w + c);
        f32x4 w1 = *(const f32x4*)(time_w + c + 4);
        f32x4 t0 = *(const f32x4*)(time_b + c);
        f32x4 t1 = *(const f32x4*)(time_b + c + 4);
        f16x8 h;
        h[0] = (_Float16)tenc(dt, w0[0], t0[0]); h[1] = (_Float16)tenc(dt, w0[1], t0[1]);
        h[2] = (_Float16)tenc(dt, w0[2], t0[2]); h[3] = (_Float16)tenc(dt, w0[3], t0[3]);
        h[4] = (_Float16)tenc(dt, w1[0], t1[0]); h[5] = (_Float16)tenc(dt, w1[1], t1[1]);
        h[6] = (_Float16)tenc(dt, w1[2], t1[2]); h[7] = (_Float16)tenc(dt, w1[3], t1[3]);
        *(f16x8*)(rawb + SWA(r, (48 + g) * 16)) = h;
    }
    __syncthreads();

    int wv = tid >> 6, lane = tid & 63;
    int arow = lane & 15, kg = lane >> 4;

    f32x4 acc1[2][4];
    #pragma unroll
    for (int c = 0; c < 2; c++)
        #pragma unroll
        for (int rt = 0; rt < 4; rt++) acc1[c][rt] = z4();
    for (int ks = 0; ks < 16; ks++) {
        f16x8 a[4];
        #pragma unroll
        for (int rt = 0; rt < 4; rt++)
            a[rt] = *(const f16x8*)(rawb + SWA(rt * 16 + arow, ks * 64 + kg * 16));
        #pragma unroll
        for (int c = 0; c < 2; c++) {
            f16x8 b = *(const f16x8*)(W1h + (((size_t)(wv * 2 + c) * 16 + ks) * 64 + lane) * 8);
            #pragma unroll
            for (int rt = 0; rt < 4; rt++)
                acc1[c][rt] = MFMA16(a[rt], b, acc1[c][rt]);
        }
    }
    __syncthreads();

    #pragma unroll
    for (int c = 0; c < 2; c++) {
        int col = (wv * 2 + c) * 16 + arow;
        float bb = b1[col];
        #pragma unroll
        for (int rt = 0; rt < 4; rt++)
            #pragma unroll
            for (int rg = 0; rg < 4; rg++) {
                int row = rt * 16 + kg * 4 + rg;
                float v = fmaxf(acc1[c][rt][rg] + bb, 0.f);
                *(_Float16*)(rawb + SWA(row, 384 + col * 2)) = (_Float16)v;
            }
    }
    __syncthreads();

    f32x4 acc2[4];
    #pragma unroll
    for (int rt = 0; rt < 4; rt++) acc2[rt] = z4();
    for (int ks = 0; ks < 8; ks++) {
        f16x8 b = *(const f16x8*)(W2h + (((size_t)wv * 8 + ks) * 64 + lane) * 8);
        #pragma unroll
        for (int rt = 0; rt < 4; rt++) {
            f16x8 a = *(const f16x8*)(rawb + SWA(rt * 16 + arow, 384 + ks * 64 + kg * 16));
            acc2[rt] = MFMA16(a, b, acc2[rt]);
        }
    }
    __syncthreads();

    {
        int col = wv * 16 + arow;
        float bb = b2[col];
        #pragma unroll
        for (int rt = 0; rt < 4; rt++)
            #pragma unroll
            for (int rg = 0; rg < 4; rg++) {
                int row = rt * 16 + kg * 4 + rg;
                *(_Float16*)(rawb + SWA(row, 384 + col * 2)) =
                    (_Float16)(acc2[rt][rg] + bb);
            }
    }
    __syncthreads();

    f32x4 aR[4], aZ[4], aNi[4], aNh[4];
    #pragma unroll
    for (int rt = 0; rt < 4; rt++) { aR[rt] = z4(); aZ[rt] = z4(); aNi[rt] = z4(); aNh[rt] = z4(); }
    for (int ks = 0; ks < 4; ks++) {
        f16x8 bi_ = ldw4(Wih, wv, ks, lane);
        f16x8 bh_ = ldw4(Whh, wv, ks, lane);
        #pragma unroll
        for (int rt = 0; rt < 4; rt++) {
            f16x8 m = *(const f16x8*)(rawb + SWA(rt * 16 + arow, 384 + ks * 64 + kg * 16));
            f16x8 hh = *(const f16x8*)(rawb + SWA(rt * 16 + arow, ks * 64 + kg * 16));
            aR[rt] = MFMA16(m, bi_, aR[rt]);
            aR[rt] = MFMA16(hh, bh_, aR[rt]);
        }
    }
    for (int ks = 0; ks < 4; ks++) {
        f16x8 bi_ = ldw4(Wih, 8 + wv, ks, lane);
        f16x8 bh_ = ldw4(Whh, 8 + wv, ks, lane);
        #pragma unroll
        for (int rt = 0; rt < 4; rt++) {
            f16x8 m = *(const f16x8*)(rawb + SWA(rt * 16 + arow, 384 + ks * 64 + kg * 16));
            f16x8 hh = *(const f16x8*)(rawb + SWA(rt * 16 + arow, ks * 64 + kg * 16));
            aZ[rt] = MFMA16(m, bi_, aZ[rt]);
            aZ[rt] = MFMA16(hh, bh_, aZ[rt]);
        }
    }
    for (int ks = 0; ks < 4; ks++) {
        f16x8 bi_ = ldw4(Wih, 16 + wv, ks, lane);
        f16x8 bh_ = ldw4(Whh, 16 + wv, ks, lane);
        #pragma unroll
        for (int rt = 0; rt < 4; rt++) {
            f16x8 m = *(const f16x8*)(rawb + SWA(rt * 16 + arow, 384 + ks * 64 + kg * 16));
            f16x8 hh = *(const f16x8*)(rawb + SWA(rt * 16 + arow, ks * 64 + kg * 16));
            aNi[rt] = MFMA16(m, bi_, aNi[rt]);
            aNh[rt] = MFMA16(hh, bh_, aNh[rt]);
        }
    }

    {
        int col = wv * 16 + arow;
        float bir = bi[col],        bhr = bh[col];
        float biz = bi[128 + col],  bhz = bh[128 + col];
        float bin_ = bi[256 + col], bhn_ = bh[256 + col];
        #pragma unroll
        for (int rt = 0; rt < 4; rt++)
            #pragma unroll
            for (int rg = 0; rg < 4; rg++) {
                int row = rt * 16 + kg * 4 + rg;
                int rr = r0 + row;
                if (rr < cnt) {
                    float r_ = fsigm(aR[rt][rg] + bir + bhr);
                    float zg = fsigm(aZ[rt][rg] + biz + bhz);
                    float ng = ftanh(aNi[rt][rg] + bin_ + r_ * (aNh[rt][rg] + bhn_));
                    float om = (float)*(const _Float16*)(rawb + SWA(row, col * 2));
                    new_mem[(size_t)rr * 128 + col] = (_Float16)((1.f - zg) * ng + zg * om);
                }
            }
    }
}

// k_feat: feat[n] = (updated ? new_mem[inv[n]] : memory[n]) + node_feats[n], f16.
// Only for referenced nodes (mask). Reads are non-temporal (read-once streams).
__global__ __launch_bounds__(256)
void k_feat(const int* __restrict__ inv, const char* __restrict__ mask,
            const _Float16* __restrict__ new_mem,
            const float* __restrict__ memory, const float* __restrict__ node_feats,
            _Float16* __restrict__ feat)
{
    int idx = blockIdx.x * 256 + threadIdx.x;
    if (idx >= NN * 16) return;
    int n = idx >> 4, g = idx & 15;
    if (!mask[n]) return;
    int c = g * 8;
    int iv = inv[n];
    f32x4 n0 = __builtin_nontemporal_load((const f32x4*)(node_feats + (size_t)n * 128 + c));
    f32x4 n1 = __builtin_nontemporal_load((const f32x4*)(node_feats + (size_t)n * 128 + c + 4));
    f16x8 o;
    if (iv >= 0) {
        f16x8 mv = *(const f16x8*)(new_mem + (size_t)iv * 128 + c);
        o[0] = (_Float16)((float)mv[0] + n0[0]); o[1] = (_Float16)((float)mv[1] + n0[1]);
        o[2] = (_Float16)((float)mv[2] + n0[2]); o[3] = (_Float16)((float)mv[3] + n0[3]);
        o[4] = (_Float16)((float)mv[4] + n1[0]); o[5] = (_Float16)((float)mv[5] + n1[1]);
        o[6] = (_Float16)((float)mv[6] + n1[2]); o[7] = (_Float16)((float)mv[7] + n1[3]);
    } else {
        f32x4 m0 = __builtin_nontemporal_load((const f32x4*)(memory + (size_t)n * 128 + c));
        f32x4 m1 = __builtin_nontemporal_load((const f32x4*)(memory + (size_t)n * 128 + c + 4));
        o[0] = (_Float16)(m0[0] + n0[0]); o[1] = (_Float16)(m0[1] + n0[1]);
        o[2] = (_Float16)(m0[2] + n0[2]); o[3] = (_Float16)(m0[3] + n0[3]);
        o[4] = (_Float16)(m1[0] + n1[0]); o[5] = (_Float16)(m1[1] + n1[1]);
        o[6] = (_Float16)(m1[2] + n1[2]); o[7] = (_Float16)(m1[3] + n1[3]);
    }
    *(f16x8*)(feat + (size_t)n * 128 + c) = o;
}

// ---------------- Stage 2 (R12-exact) ----------------
__global__ __launch_bounds__(512, 2)
void k2b(const int* __restrict__ src_nodes, const int* __restrict__ dst_nodes,
         const int* __restrict__ neg_nodes, const _Float16* __restrict__ feat,
         const _Float16* __restrict__ WqLh, const float* __restrict__ bq2,
         const _Float16* __restrict__ Wkth,
         _Float16* __restrict__ sfeat, _Float16* __restrict__ qk_ws)
{
    __shared__ char lds[24 * 1024];    // [0,8K): sfeat tile; [8K,24K): q tile
    __shared__ int snode[32];
    int tid = threadIdx.x;
    int r0 = blockIdx.x * 32;

    if (tid < 32) {
        int q = r0 + tid;
        snode[tid] = (q < BB) ? src_nodes[q] : (q < 2 * BB) ? dst_nodes[q - BB] : neg_nodes[q - 2 * BB];
    }
    __syncthreads();

    {
        int r = tid >> 4, g = tid & 15;
        f16x8 v = *(const f16x8*)(feat + (size_t)snode[r] * 128 + g * 8);
        *(f16x8*)(&lds[r * 256 + ((g * 16) ^ ((r & 7) << 4))]) = v;
        *(f16x8*)(sfeat + (size_t)(r0 + r) * 128 + g * 8) = v;
    }
    __syncthreads();

    int wv = tid >> 6, lane = tid & 63;
    int arow = lane & 15, kg = lane >> 4;

    f32x4 acc[2][2];
    #pragma unroll
    for (int c = 0; c < 2; c++) { acc[c][0] = z4(); acc[c][1] = z4(); }
    for (int ks = 0; ks < 4; ks++) {
        f16x8 a0 = *(const f16x8*)(&lds[arow * 256 + ((ks * 64 + kg * 16) ^ ((arow & 7) << 4))]);
        f16x8 a1 = *(const f16x8*)(&lds[(16 + arow) * 256 + ((ks * 64 + kg * 16) ^ ((arow & 7) << 4))]);
        #pragma unroll
        for (int c = 0; c < 2; c++) {
            f16x8 b = *(const f16x8*)(WqLh + (((size_t)(wv * 2 + c) * 4 + ks) * 64 + lane) * 8);
            acc[c][0] = MFMA16(a0, b, acc[c][0]);
            acc[c][1] = MFMA16(a1, b, acc[c][1]);
        }
    }
    #pragma unroll
    for (int c = 0; c < 2; c++) {
        int col = (wv * 2 + c) * 16 + arow;
        float bb = bq2[col];
        #pragma unroll
        for (int rt = 0; rt < 2; rt++)
            #pragma unroll
            for (int rg = 0; rg < 4; rg++) {
                int row = rt * 16 + kg * 4 + rg;
                *(_Float16*)(&lds[8192 + row * 512 + ((col * 2) ^ ((row & 7) << 4))]) =
                    (_Float16)(acc[c][rt][rg] + bb);
            }
    }
    __syncthreads();

    int h = wv >> 2;
    f32x4 acc2[6][2];
    #pragma unroll
    for (int c = 0; c < 6; c++) { acc2[c][0] = z4(); acc2[c][1] = z4(); }
    for (int ks = 0; ks < 4; ks++) {
        f16x8 a0 = *(const f16x8*)(&lds[8192 + arow * 512 +
                    ((h * 256 + ks * 64 + kg * 16) ^ ((arow & 7) << 4))]);
        f16x8 a1 = *(const f16x8*)(&lds[8192 + (16 + arow) * 512 +
                    ((h * 256 + ks * 64 + kg * 16) ^ ((arow & 7) << 4))]);
        #pragma unroll
        for (int c = 0; c < 6; c++) {
            int cgh = (wv & 3) * 6 + c;
            f16x8 b = *(const f16x8*)(Wkth + (size_t)h * 49152 +
                       (((size_t)cgh * 4 + ks) * 64 + lane) * 8);
            acc2[c][0] = MFMA16(a0, b, acc2[c][0]);
            acc2[c][1] = MFMA16(a1, b, acc2[c][1]);
        }
    }
    #pragma unroll
    for (int c = 0; c < 6; c++) {
        int cgh = (wv & 3) * 6 + c;
        int col = h * 384 + cgh * 16 + arow;
        #pragma unroll
        for (int rt = 0; rt < 2; rt++)
            #pragma unroll
            for (int rg = 0; rg < 4; rg++) {
                int row = rt * 16 + kg * 4 + rg;
                qk_ws[(size_t)(r0 + row) * 768 + col] = (_Float16)acc2[c][rt][rg];
            }
    }
}

// generic 32-row-tile MFMA GEMM, fragment-ordered B (used for Wv fold only).
template<int KD, int NFRAG, bool RELU>
__global__ __launch_bounds__(256, 4)
void k_gemm(const _Float16* __restrict__ A, int lda, int a_ys,
            const _Float16* __restrict__ B, int b_ys,
            const float* __restrict__ bias, int bias_ys,
            _Float16* __restrict__ C, int ldc, int c_ys,
            float* __restrict__ C32,
            const int* __restrict__ rowmask)
{
    constexpr int ROWB = KD * 2;
    __shared__ char As[32 * ROWB];
    int tid = threadIdx.x;
    int r0 = blockIdx.x * 32;
    int aoff = blockIdx.y * a_ys;
    const _Float16* Bp = B + (size_t)blockIdx.y * b_ys;
    int coff = blockIdx.y * c_ys;

    #pragma unroll
    for (int t = 0; t < (32 * KD / 8) / 256; t++) {
        int gi = tid + t * 256;
        int r = gi / (KD / 8), g = gi % (KD / 8);
        f16x8 v = *(const f16x8*)(A + (size_t)(r0 + r) * lda + aoff + g * 8);
        *(f16x8*)(&As[r * ROWB + ((g * 16) ^ ((r & 7) << 4))]) = v;
    }
    __syncthreads();

    int wv = tid >> 6, lane = tid & 63;
    int arow = lane & 15, kg = lane >> 4;
    f32x4 acc[NFRAG][2];
    #pragma unroll
    for (int c = 0; c < NFRAG; c++) { acc[c][0] = z4(); acc[c][1] = z4(); }

    #pragma unroll
    for (int ks = 0; ks < KD / 32; ks++) {
        f16x8 a0 = *(const f16x8*)(&As[arow * ROWB + ((ks * 64 + kg * 16) ^ ((arow & 7) << 4))]);
        f16x8 a1 = *(const f16x8*)(&As[(16 + arow) * ROWB + ((ks * 64 + kg * 16) ^ ((arow & 7) << 4))]);
        #pragma unroll
        for (int c = 0; c < NFRAG; c++) {
            f16x8 b = *(const f16x8*)(Bp +
                (((size_t)(wv * NFRAG + c) * (KD / 32) + ks) * 64 + lane) * 8);
            acc[c][0] = MFMA16(a0, b, acc[c][0]);
            acc[c][1] = MFMA16(a1, b, acc[c][1]);
        }
    }

    #pragma unroll
    for (int c = 0; c < NFRAG; c++) {
        int cg = (wv * NFRAG + c) * 16 + arow;
        float bb = bias ? bias[blockIdx.y * bias_ys + cg] : 0.f;
        #pragma unroll
        for (int rt = 0; rt < 2; rt++)
            #pragma unroll
            for (int rg = 0; rg < 4; rg++) {
                int grow = r0 + rt * 16 + kg * 4 + rg;
                float v = acc[c][rt][rg] + bb;
                if (RELU) v = fmaxf(v, 0.f);
                if (rowmask && rowmask[grow]) v = 0.f;
                if (C)   C[(size_t)grow * ldc + coff + cg] = (_Float16)v;
                if (C32) C32[(size_t)grow * ldc + coff + cg] = v;
            }
    }
}

// k2d: attention core (R12-exact; neighbor rows have cross-query reuse -> keep cached).
__global__ __launch_bounds__(256)
void k2d(const int* __restrict__ neighbors, const int* __restrict__ nb_eidx,
         const int* __restrict__ nb_et, const int* __restrict__ edge_times,
         const _Float16* __restrict__ feat,
         const float* __restrict__ edge_feats, const float* __restrict__ time_w,
         const float* __restrict__ time_b,
         _Float16* __restrict__ qk_wsum, int* __restrict__ allm)
{
    int tid = threadIdx.x;
    int qi = blockIdx.x * 4 + (tid >> 6);
    int lane = tid & 63;
    int h = lane >> 5, l32 = lane & 31;
    int c0 = l32 * 4;

    f32x4 tw = *(const f32x4*)(time_w + c0);
    f32x4 tb = *(const f32x4*)(time_b + c0);

    const _Float16* qkp = qk_wsum + (size_t)qi * 768 + h * 384;
    f16x4 t0 = *(const f16x4*)(qkp + c0);
    f16x4 t1 = *(const f16x4*)(qkp + 128 + c0);
    f16x4 t2 = *(const f16x4*)(qkp + 256 + c0);
    float qk0[4], qk1[4], qk2[4];
    #pragma unroll
    for (int t = 0; t < 4; t++) { qk0[t] = (float)t0[t]; qk1[t] = (float)t1[t]; qk2[t] = (float)t2[t]; }

    float ts = (float)edge_times[qi & (BB - 1)];
    float m_run = -3.0e38f, l_run = 0.f;
    float w0[4] = {0,0,0,0}, w1[4] = {0,0,0,0}, w2[4] = {0,0,0,0};
    int anyv = 0;
    const float inv_sqrt = 0.08838834764831845f;

    int base = qi * KK;
    int nb_c = neighbors[base];
    int ei_c = nb_eidx[base];
    int et_c = nb_et[base];
    f16x4 fv;
    f32x4 ef;
    {
        fv = *(const f16x4*)(feat + (size_t)nb_c * 128 + c0);
        ef = *(const f32x4*)(edge_feats + (size_t)ei_c * 128 + c0);
    }

    for (int j = 0; j < KK; j++) {
        int nb_n = 0, ei_n = 0, et_n = 0;
        f16x4 fv_n = {0,0,0,0};
        f32x4 ef_n = {0,0,0,0};
        if (j + 1 < KK) {
            nb_n = neighbors[base + j + 1];
            ei_n = nb_eidx[base + j + 1];
            et_n = nb_et[base + j + 1];
            fv_n = *(const f16x4*)(feat + (size_t)nb_n * 128 + c0);
            ef_n = *(const f32x4*)(edge_feats + (size_t)ei_n * 128 + c0);
        }

        float dtf = ts - (float)et_c;
        anyv |= (nb_c != 0);
        float k0[4] = { (float)fv[0], (float)fv[1], (float)fv[2], (float)fv[3] };
        float k1[4] = { tenc(dtf, tw[0], tb[0]), tenc(dtf, tw[1], tb[1]),
                        tenc(dtf, tw[2], tb[2]), tenc(dtf, tw[3], tb[3]) };
        float k2[4] = { ef[0], ef[1], ef[2], ef[3] };

        float sp = 0.f;
        #pragma unroll
        for (int t = 0; t < 4; t++)
            sp += qk0[t] * k0[t] + qk1[t] * k1[t] + qk2[t] * k2[t];
        sp += __shfl_xor(sp, 1, 32);
        sp += __shfl_xor(sp, 2, 32);
        sp += __shfl_xor(sp, 4, 32);
        sp += __shfl_xor(sp, 8, 32);
        sp += __shfl_xor(sp, 16, 32);

        float s = sp * inv_sqrt;
        if (nb_c == 0) s = -1e9f;
        float m_new = fmaxf(m_run, s);
        float sc = __expf(m_run - m_new);
        float p = __expf(s - m_new);
        l_run = l_run * sc + p;
        #pragma unroll
        for (int t = 0; t < 4; t++) {
            w0[t] = w0[t] * sc + p * k0[t];
            w1[t] = w1[t] * sc + p * k1[t];
            w2[t] = w2[t] * sc + p * k2[t];
        }
        m_run = m_new;

        nb_c = nb_n; ei_c = ei_n; et_c = et_n;
        fv = fv_n; ef = ef_n;
    }

    float linv = __builtin_amdgcn_rcpf(l_run);
    _Float16* wp = qk_wsum + (size_t)qi * 768 + h * 384;
    f16x4 o0, o1, o2;
    #pragma unroll
    for (int t = 0; t < 4; t++) {
        o0[t] = (_Float16)(w0[t] * linv);
        o1[t] = (_Float16)(w1[t] * linv);
        o2[t] = (_Float16)(w2[t] * linv);
    }
    *(f16x4*)(wp + c0) = o0;
    *(f16x4*)(wp + 128 + c0) = o1;
    *(f16x4*)(wp + 256 + c0) = o2;
    if (lane == 0) allm[qi] = anyv ? 0 : 1;
}

// k2t2: fused tail (R12-exact).
__global__ __launch_bounds__(256, 2)
void k2t2(const _Float16* __restrict__ ctx, const _Float16* __restrict__ sfeat,
          const _Float16* __restrict__ Woh, const float* __restrict__ bo,
          const _Float16* __restrict__ mW1h, const float* __restrict__ mb1,
          const _Float16* __restrict__ mW2h, const float* __restrict__ mb2,
          const int* __restrict__ allm, float* __restrict__ out)
{
    __shared__ char lds[48 * 1024];
    int tid = threadIdx.x;
    int r0 = blockIdx.x * 32;

    #pragma unroll
    for (int t = 0; t < 4; t++) {
        int gi = tid + t * 256;
        int r = gi >> 5, g = gi & 31;
        f16x8 v = *(const f16x8*)(ctx + (size_t)(r0 + r) * 256 + g * 8);
        *(f16x8*)(&lds[r * 512 + ((g * 16) ^ ((r & 7) << 4))]) = v;
    }
    __syncthreads();

    int wv = tid >> 6, lane = tid & 63;
    int arow = lane & 15, kg = lane >> 4;

    f32x4 acc[4][2];
    #pragma unroll
    for (int c = 0; c < 4; c++) { acc[c][0] = z4(); acc[c][1] = z4(); }
    for (int ks = 0; ks < 8; ks++) {
        f16x8 a0 = *(const f16x8*)(&lds[arow * 512 + ((ks * 64 + kg * 16) ^ ((arow & 7) << 4))]);
        f16x8 a1 = *(const f16x8*)(&lds[(16 + arow) * 512 + ((ks * 64 + kg * 16) ^ ((arow & 7) << 4))]);
        #pragma unroll
        for (int c = 0; c < 4; c++) {
            f16x8 b = *(const f16x8*)(Woh + (((size_t)(wv * 4 + c) * 8 + ks) * 64 + lane) * 8);
            acc[c][0] = MFMA16(a0, b, acc[c][0]);
            acc[c][1] = MFMA16(a1, b, acc[c][1]);
        }
    }
    #pragma unroll
    for (int c = 0; c < 4; c++) {
        int col = (wv * 4 + c) * 16 + arow;
        float bb = bo[col];
        #pragma unroll
        for (int rt = 0; rt < 2; rt++)
            #pragma unroll
            for (int rg = 0; rg < 4; rg++) {
                int row = rt * 16 + kg * 4 + rg;
                float v = allm[r0 + row] ? 0.f : (acc[c][rt][rg] + bb);
                *(_Float16*)(&lds[16384 + row * 768 + ((col * 2) ^ ((row & 7) << 4))]) = (_Float16)v;
            }
    }
    #pragma unroll
    for (int t = 0; t < 2; t++) {
        int gi = tid + t * 256;
        int r = gi >> 4, g = gi & 15;
        f16x8 v = *(const f16x8*)(sfeat + (size_t)(r0 + r) * 128 + g * 8);
        *(f16x8*)(&lds[16384 + r * 768 + ((512 + g * 16) ^ ((r & 7) << 4))]) = v;
    }
    __syncthreads();

    f32x4 acc2[2][2];
    #pragma unroll
    for (int c = 0; c < 2; c++) { acc2[c][0] = z4(); acc2[c][1] = z4(); }
    for (int ks = 0; ks < 12; ks++) {
        f16x8 a0 = *(const f16x8*)(&lds[16384 + arow * 768 + ((ks * 64 + kg * 16) ^ ((arow & 7) << 4))]);
        f16x8 a1 = *(const f16x8*)(&lds[16384 + (16 + arow) * 768 + ((ks * 64 + kg * 16) ^ ((arow & 7) << 4))]);
        #pragma unroll
        for (int c = 0; c < 2; c++) {
            f16x8 b = *(const f16x8*)(mW1h + (((size_t)(wv * 2 + c) * 12 + ks) * 64 + lane) * 8);
            acc2[c][0] = MFMA16(a0, b, acc2[c][0]);
            acc2[c][1] = MFMA16(a1, b, acc2[c][1]);
        }
    }
    #pragma unroll
    for (int c = 0; c < 2; c++) {
        int col = (wv * 2 + c) * 16 + arow;
        float bb = mb1[col];
        #pragma unroll
        for (int rt = 0; rt < 2; rt++)
            #pragma unroll
            for (int rg = 0; rg < 4; rg++) {
                int row = rt * 16 + kg * 4 + rg;
                float v = fmaxf(acc2[c][rt][rg] + bb, 0.f);
                *(_Float16*)(&lds[40960 + row * 256 + ((col * 2) ^ ((row & 7) << 4))]) = (_Float16)v;
            }
    }
    __syncthreads();

    f32x4 acc3[2][2];
    #pragma unroll
    for (int c = 0; c < 2; c++) { acc3[c][0] = z4(); acc3[c][1] = z4(); }
    for (int ks = 0; ks < 4; ks++) {
        f16x8 a0 = *(const f16x8*)(&lds[40960 + arow * 256 + ((ks * 64 + kg * 16) ^ ((arow & 7) << 4))]);
        f16x8 a1 = *(const f16x8*)(&lds[40960 + (16 + arow) * 256 + ((ks * 64 + kg * 16) ^ ((arow & 7) << 4))]);
        #pragma unroll
        for (int c = 0; c < 2; c++) {
            f16x8 b = *(const f16x8*)(mW2h + (((size_t)(wv * 2 + c) * 4 + ks) * 64 + lane) * 8);
            acc3[c][0] = MFMA16(a0, b, acc3[c][0]);
            acc3[c][1] = MFMA16(a1, b, acc3[c][1]);
        }
    }
    #pragma unroll
    for (int c = 0; c < 2; c++) {
        int col = (wv * 2 + c) * 16 + arow;
        float bb = mb2[col];
        #pragma unroll
        for (int rt = 0; rt < 2; rt++)
            #pragma unroll
            for (int rg = 0; rg < 4; rg++) {
                int row = rt * 16 + kg * 4 + rg;
                out[(size_t)(r0 + row) * 128 + col] = acc3[c][rt][rg] + bb;
            }
    }
}

extern "C" void kernel_launch(void* const* d_in, const int* in_sizes, int n_in,
                              void* d_out, int out_size, void* d_ws, size_t ws_size,
                              hipStream_t stream) {
    (void)in_sizes; (void)n_in; (void)out_size; (void)ws_size;
    const int* src_nodes  = (const int*)d_in[0];
    const int* dst_nodes  = (const int*)d_in[1];
    const int* neg_nodes  = (const int*)d_in[2];
    const int* edge_times = (const int*)d_in[3];
    const int* neighbors  = (const int*)d_in[4];
    const int* nb_eidx    = (const int*)d_in[5];
    const int* nb_et      = (const int*)d_in[6];
    const int* msg_src    = (const int*)d_in[7];
    const int* msg_dst    = (const int*)d_in[8];
    const int* msg_eidx   = (const int*)d_in[9];
    const int* msg_t      = (const int*)d_in[10];
    const int* last_update= (const int*)d_in[11];
    const float* node_feats = (const float*)d_in[12];
    const float* edge_feats = (const float*)d_in[13];
    const float* memory     = (const float*)d_in[14];
    const float* time_w = (const float*)d_in[15];
    const float* time_b = (const float*)d_in[16];
    const float* W1 = (const float*)d_in[17];
    const float* b1 = (const float*)d_in[18];
    const float* W2 = (const float*)d_in[19];
    const float* b2 = (const float*)d_in[20];
    const float* gWi = (const float*)d_in[21];
    const float* gWh = (const float*)d_in[22];
    const float* gbi = (const float*)d_in[23];
    const float* gbh = (const float*)d_in[24];
    const float* Wq = (const float*)d_in[25];
    const float* bq = (const float*)d_in[26];
    const float* Wk = (const float*)d_in[27];
    const float* bk = (const float*)d_in[28];
    const float* Wv = (const float*)d_in[29];
    const float* bv = (const float*)d_in[30];
    const float* Wo = (const float*)d_in[31];
    const float* bo = (const float*)d_in[32];
    const float* mW1 = (const float*)d_in[33];
    const float* mb1 = (const float*)d_in[34];
    const float* mW2 = (const float*)d_in[35];
    const float* mb2 = (const float*)d_in[36];
    float* out = (float*)d_out;
    (void)bk;

    char* w = (char*)d_ws;
    int* lastpos = (int*)w;
    int* inv  = lastpos + NN;
    int* comp = inv + NN;
    int* count = comp + NN;
    int* bcnt = count + 1;
    int* boff = bcnt + NBLK;
    char* mask = (char*)(boff + NBLK);                // NN bytes
    size_t off = ((size_t)(3 * NN + 1 + 2 * NBLK) * 4 + NN + 255) & ~(size_t)255;
    _Float16* new_mem = (_Float16*)(w + off);         // MM*128 f16
    size_t foff = off + (size_t)MM * 128 * 2;
    _Float16* feat = (_Float16*)(w + foff);           // NN*128 f16
    size_t woff = foff + (size_t)NN * 128 * 2;

    _Float16* Hpool = (_Float16*)(w + woff);          // 622592 f16, fragment order
    _Float16* W1h  = Hpool;
    _Float16* W2h  = Hpool + 131072;
    _Float16* Wih  = Hpool + 163840;
    _Float16* Whh  = Hpool + 212992;
    _Float16* WqLh = Hpool + 262144;
    _Float16* Wvh  = Hpool + 294912;
    _Float16* Woh  = Hpool + 393216;
    _Float16* mW1h = Hpool + 458752;
    _Float16* mW2h = Hpool + 507904;
    _Float16* Wkth = Hpool + 524288;
    float* bq2 = (float*)(Hpool + 622592);            // 256 f32
    size_t boff2 = woff + (size_t)622592 * 2 + 1024;

    _Float16* ctx   = (_Float16*)(w + boff2);         // Q3*256
    _Float16* qk_ws = ctx + (size_t)Q3 * 256;         // Q3*768
    _Float16* sfeat = qk_ws + (size_t)Q3 * 768;       // Q3*128
    int* allm       = (int*)(sfeat + (size_t)Q3 * 128);

    k_init<<<dim3(NBLK), dim3(256), 0, stream>>>(lastpos, mask);
    k_scatter<<<dim3((MM + 255) / 256), dim3(256), 0, stream>>>(msg_src, lastpos);
    k_mark<<<dim3((Q3 + Q3 * KK + 255) / 256), dim3(256), 0, stream>>>(
        src_nodes, dst_nodes, neg_nodes, neighbors, mask);
    k_count<<<dim3(NBLK), dim3(256), 0, stream>>>(lastpos, bcnt);
    k_scan<<<dim3(1), dim3(256), 0, stream>>>(bcnt, boff, count);
    k_fill<<<dim3(NBLK), dim3(256), 0, stream>>>(lastpos, boff, comp, inv);
    k_cvtw<<<dim3(305), dim3(256), 0, stream>>>(
        W1, W2, gWi, gWh, Wq, Wv, Wo, mW1, mW2, Wk, bq, time_b, Hpool, bq2);
    k_stage1<<<dim3((MM + 63) / 64), dim3(512), 0, stream>>>(
        comp, count, lastpos, msg_dst, msg_eidx, msg_t, last_update,
        memory, edge_feats, time_w, time_b,
        W1h, b1, W2h, b2, Wih, Whh, gbi, gbh, new_mem);
    k_feat<<<dim3(NN * 16 / 256), dim3(256), 0, stream>>>(
        inv, mask, new_mem, memory, node_feats, feat);

    k2b<<<dim3(Q3 / 32), dim3(512), 0, stream>>>(
        src_nodes, dst_nodes, neg_nodes, feat, WqLh, bq2, Wkth, sfeat, qk_ws);
    k2d<<<dim3(Q3 / 4), dim3(256), 0, stream>>>(
        neighbors, nb_eidx, nb_et, edge_times, feat,
        edge_feats, time_w, time_b, qk_ws, allm);
    k_gemm<384, 2, false><<<dim3(Q3 / 32, 2), dim3(256), 0, stream>>>(
        qk_ws, 768, 384, Wvh, 49152, bv, 128, ctx, 256, 128, nullptr, nullptr);
    k2t2<<<dim3(Q3 / 32), dim3(256), 0, stream>>>(
        ctx, sfeat, Woh, bo, mW1h, mb1, mW2h, mb2, allm, out);
}